// Round 1
// baseline (12171.901 us; speedup 1.0000x reference)
//
#include <hip/hip_runtime.h>
#include <cstdint>
#include <cstddef>

#define T_LEN 2048
#define BATCH 128

__device__ __forceinline__ float bcast(float v, int l) {
  return __uint_as_float(__builtin_amdgcn_readlane(__float_as_uint(v), (unsigned)l));
}
__device__ __forceinline__ float sigm(float x) {
  return __builtin_amdgcn_rcpf(1.0f + exp2f(-1.4426950408889634f * x));
}
__device__ __forceinline__ float tanh_fast(float x) {
  return 1.0f - 2.0f * __builtin_amdgcn_rcpf(1.0f + exp2f(2.8853900817779268f * x));
}

// ---------------- proj: in0[t*B+b, j] = relu(x[b,t,:] . w_proj[j,:] + b_proj[j])
__global__ __launch_bounds__(256) void proj_kernel(
    const float* __restrict__ x, const float* __restrict__ w_proj,
    const float* __restrict__ b_proj, float* __restrict__ in0) {
  int R = blockIdx.x * 4 + (threadIdx.x >> 6);  // R = t*BATCH + b
  int j = threadIdx.x & 63;
  int t = R >> 7;
  int b = R & 127;
  const float* xr = x + ((size_t)b * T_LEN + t) * 32;
  const float* wr = w_proj + j * 32;
  float a = b_proj[j];
#pragma unroll
  for (int k = 0; k < 32; ++k) a = fmaf(xr[k], wr[k], a);
  in0[(size_t)R * 64 + j] = fmaxf(a, 0.f);
}

// ---------------- persistent bidirectional LSTM layer
// block = (batch b, direction dir); thread tid owns gate-row g = tid (i,f,g,o x 64)
template <int DIN>
__global__ __launch_bounds__(256, 1) void lstm_kernel(
    const float* __restrict__ in,    // [T, B, DIN]
    float* __restrict__ out,         // [T, B, 128] (dir0 -> [0:64), dir1 -> [64:128))
    const float* __restrict__ w_ih,  // [2, 256, DIN]
    const float* __restrict__ w_hh,  // [2, 256, 64]
    const float* __restrict__ bias)  // [2, 256]
{
  const int tid = threadIdx.x;
  const int dir = blockIdx.x & 1;
  const int b = blockIdx.x >> 1;
  const int j = tid & 63;

  float wih[DIN];
  {
    const float* p = w_ih + ((size_t)(dir * 256 + tid)) * DIN;
#pragma unroll
    for (int k = 0; k < DIN; ++k) wih[k] = p[k];
  }
  float whh[64];
  {
    const float* p = w_hh + ((size_t)(dir * 256 + tid)) * 64;
#pragma unroll
    for (int k = 0; k < 64; ++k) whh[k] = p[k];
  }
  const float bz = bias[dir * 256 + tid];

  __shared__ float ring[32][DIN];  // input rows in traversal order, 32-slot ring
  __shared__ float zb[2][256];     // gate pre-activations, double buffered

  // preload rows 0..31 (traversal order; bwd maps r -> T-1-r)
#pragma unroll
  for (int i = 0; i < (32 * DIN) / 256; ++i) {
    int idx = tid + 256 * i;
    int r = idx / DIN;
    int col = idx % DIN;
    int t = dir ? (T_LEN - 1 - r) : r;
    ring[r][col] = in[((size_t)t * BATCH + b) * DIN + col];
  }
  __syncthreads();

  float c = 0.f, h = 0.f;
  const int SREG = (16 * DIN) / 256;  // 4 (DIN=64) or 8 (DIN=128)

  for (int s = 0; s < T_LEN; ++s) {
    const int p = s & 1;

    // ---- refill issue: rows s+16 .. s+31 (loads issued early, LDS-written late)
    float stg[SREG];
    const bool refill = ((s & 15) == 0) && (s + 16 < T_LEN);
    if (refill) {
#pragma unroll
      for (int i = 0; i < SREG; ++i) {
        int idx = tid + 256 * i;
        int r = s + 16 + idx / DIN;
        int col = idx % DIN;
        int t = dir ? (T_LEN - 1 - r) : r;
        stg[i] = in[((size_t)t * BATCH + b) * DIN + col];
      }
    }

    // ---- current input row from ring (lane j holds row[j], row[64+j])
    const int slot = s & 31;
    float vin0 = ring[slot][j];
    float vin1 = 0.f;
    if constexpr (DIN == 128) vin1 = ring[slot][64 + j];

    float acc = bz;
#pragma unroll
    for (int k = 0; k < 64; ++k) acc = fmaf(bcast(vin0, k), wih[k], acc);
    if constexpr (DIN == 128) {
#pragma unroll
      for (int k = 0; k < 64; ++k) acc = fmaf(bcast(vin1, k), wih[64 + k], acc);
    }

    // ---- previous step's gates (overlaps exp latency with input-dot issue)
    if (s > 0) {
      float zi = zb[1 - p][j];
      float zf = zb[1 - p][64 + j];
      float zg = zb[1 - p][128 + j];
      float zo = zb[1 - p][192 + j];
      float ig = sigm(zi), fg = sigm(zf), gg = tanh_fast(zg), og = sigm(zo);
      c = fmaf(fg, c, ig * gg);
      h = og * tanh_fast(c);
      if (tid < 64) {
        int tp = dir ? (T_LEN - s) : (s - 1);  // t of step s-1
        out[((size_t)tp * BATCH + b) * 128 + dir * 64 + j] = h;
      }
    }

    // ---- recurrent dot (needs fresh h)
#pragma unroll
    for (int k = 0; k < 64; ++k) acc = fmaf(bcast(h, k), whh[k], acc);

    zb[p][tid] = acc;
    if (refill) {
#pragma unroll
      for (int i = 0; i < SREG; ++i) {
        int idx = tid + 256 * i;
        int r = s + 16 + idx / DIN;
        int col = idx % DIN;
        ring[r & 31][col] = stg[i];
      }
    }
    __syncthreads();
  }

  // ---- final gates (step T-1, parity 1)
  {
    float zi = zb[1][j];
    float zf = zb[1][64 + j];
    float zg = zb[1][128 + j];
    float zo = zb[1][192 + j];
    float ig = sigm(zi), fg = sigm(zf), gg = tanh_fast(zg), og = sigm(zo);
    c = fmaf(fg, c, ig * gg);
    h = og * tanh_fast(c);
    if (tid < 64) {
      int tp = dir ? 0 : (T_LEN - 1);
      out[((size_t)tp * BATCH + b) * 128 + dir * 64 + j] = h;
    }
  }
}

// ---------------- attention: scores + softmax + pooled, one block per batch row
__global__ __launch_bounds__(256) void attn_kernel(
    const float* __restrict__ hs,      // [T, B, 128]
    const float* __restrict__ w_attn,  // [128]
    float* __restrict__ pooled)        // [B, 128]
{
  const int b = blockIdx.x, tid = threadIdx.x;
  __shared__ float wa[128];
  __shared__ float sc[T_LEN];
  __shared__ float red[256];
  if (tid < 128) wa[tid] = w_attn[tid];
  __syncthreads();

  float lmax = -3.4e38f;
#pragma unroll
  for (int i = 0; i < T_LEN / 256; ++i) {
    int t = tid + 256 * i;
    const float4* r4 = (const float4*)(hs + ((size_t)t * BATCH + b) * 128);
    float s = 0.f;
#pragma unroll
    for (int k = 0; k < 32; ++k) {
      float4 v = r4[k];
      s += v.x * wa[4 * k] + v.y * wa[4 * k + 1] + v.z * wa[4 * k + 2] + v.w * wa[4 * k + 3];
    }
    sc[t] = s;
    lmax = fmaxf(lmax, s);
  }
  red[tid] = lmax;
  __syncthreads();
  for (int off = 128; off > 0; off >>= 1) {
    if (tid < off) red[tid] = fmaxf(red[tid], red[tid + off]);
    __syncthreads();
  }
  float m = red[0];
  __syncthreads();

  float lsum = 0.f;
#pragma unroll
  for (int i = 0; i < T_LEN / 256; ++i) {
    int t = tid + 256 * i;
    float e = exp2f((sc[t] - m) * 1.4426950408889634f);
    sc[t] = e;
    lsum += e;
  }
  red[tid] = lsum;
  __syncthreads();
  for (int off = 128; off > 0; off >>= 1) {
    if (tid < off) red[tid] += red[tid + off];
    __syncthreads();
  }
  float inv = __builtin_amdgcn_rcpf(red[0]);

  if (tid < 128) {
    float a0 = 0.f, a1 = 0.f, a2 = 0.f, a3 = 0.f;
    for (int t = 0; t < T_LEN; t += 4) {
      a0 = fmaf(sc[t], hs[((size_t)t * BATCH + b) * 128 + tid], a0);
      a1 = fmaf(sc[t + 1], hs[((size_t)(t + 1) * BATCH + b) * 128 + tid], a1);
      a2 = fmaf(sc[t + 2], hs[((size_t)(t + 2) * BATCH + b) * 128 + tid], a2);
      a3 = fmaf(sc[t + 3], hs[((size_t)(t + 3) * BATCH + b) * 128 + tid], a3);
    }
    pooled[b * 128 + tid] = ((a0 + a1) + (a2 + a3)) * inv;
  }
}

// ---------------- head: BN1 -> fc1 -> relu -> fc2 -> elu -> BN2 -> fc3
__global__ __launch_bounds__(128) void head_kernel(
    const float* __restrict__ pooled,
    const float* g1, const float* be1, const float* m1, const float* v1,
    const float* w1, const float* b1, const float* w2, const float* b2,
    const float* g2, const float* be2, const float* m2, const float* v2,
    const float* w3, const float* b3, float* __restrict__ out) {
  const int b = blockIdx.x, tid = threadIdx.x;
  __shared__ float xb[128], y1[128], y2[64];
  xb[tid] = (pooled[b * 128 + tid] - m1[tid]) * rsqrtf(v1[tid] + 1e-5f) * g1[tid] + be1[tid];
  __syncthreads();
  float a = b1[tid];
#pragma unroll 8
  for (int k = 0; k < 128; ++k) a = fmaf(xb[k], w1[tid * 128 + k], a);
  y1[tid] = fmaxf(a, 0.f);
  __syncthreads();
  if (tid < 64) {
    float a2 = b2[tid];
#pragma unroll 8
    for (int k = 0; k < 128; ++k) a2 = fmaf(y1[k], w2[tid * 128 + k], a2);
    if (a2 < 0.f) a2 = exp2f(a2 * 1.4426950408889634f) - 1.0f;  // elu
    y2[tid] = (a2 - m2[tid]) * rsqrtf(v2[tid] + 1e-5f) * g2[tid] + be2[tid];
  }
  __syncthreads();
  if (tid < 3) {
    float a3 = b3[tid];
#pragma unroll
    for (int k = 0; k < 64; ++k) a3 = fmaf(y2[k], w3[tid * 64 + k], a3);
    out[b * 3 + tid] = a3;
  }
}

extern "C" void kernel_launch(void* const* d_in, const int* in_sizes, int n_in,
                              void* d_out, int out_size, void* d_ws, size_t ws_size,
                              hipStream_t stream) {
  const float* x      = (const float*)d_in[0];
  const float* w_proj = (const float*)d_in[1];
  const float* b_proj = (const float*)d_in[2];
  const float* w_ih_l0 = (const float*)d_in[3];
  const float* w_hh_l0 = (const float*)d_in[4];
  const float* b_l0    = (const float*)d_in[5];
  const float* w_ih_r  = (const float*)d_in[6];  // [3,2,256,128]
  const float* w_hh_r  = (const float*)d_in[7];  // [3,2,256,64]
  const float* b_r     = (const float*)d_in[8];  // [3,2,256]
  const float* w_attn  = (const float*)d_in[9];
  const float* g1  = (const float*)d_in[11];
  const float* be1 = (const float*)d_in[12];
  const float* m1  = (const float*)d_in[13];
  const float* v1  = (const float*)d_in[14];
  const float* w1  = (const float*)d_in[15];
  const float* b1  = (const float*)d_in[16];
  const float* w2  = (const float*)d_in[17];
  const float* b2  = (const float*)d_in[18];
  const float* g2  = (const float*)d_in[19];
  const float* be2 = (const float*)d_in[20];
  const float* m2  = (const float*)d_in[21];
  const float* v2  = (const float*)d_in[22];
  const float* w3  = (const float*)d_in[23];
  const float* b3  = (const float*)d_in[24];
  float* out = (float*)d_out;

  // ws layout: bufA [T,B,128] | bufB [T,B,128]  (in0 and pooled overlay dead regions)
  float* bufA = (float*)d_ws;
  float* bufB = bufA + (size_t)T_LEN * BATCH * 128;
  float* in0 = bufB;     // [T,B,64]; dead once layer1 starts writing bufB
  float* pooled = bufA;  // reused after layer3 no longer reads bufA

  proj_kernel<<<T_LEN * BATCH / 4, 256, 0, stream>>>(x, w_proj, b_proj, in0);
  lstm_kernel<64><<<256, 256, 0, stream>>>(in0, bufA, w_ih_l0, w_hh_l0, b_l0);
  lstm_kernel<128><<<256, 256, 0, stream>>>(bufA, bufB, w_ih_r, w_hh_r, b_r);
  lstm_kernel<128><<<256, 256, 0, stream>>>(bufB, bufA, w_ih_r + 65536, w_hh_r + 32768, b_r + 512);
  lstm_kernel<128><<<256, 256, 0, stream>>>(bufA, bufB, w_ih_r + 131072, w_hh_r + 65536, b_r + 1024);
  attn_kernel<<<BATCH, 256, 0, stream>>>(bufB, w_attn, pooled);
  head_kernel<<<BATCH, 128, 0, stream>>>(pooled, g1, be1, m1, v1, w1, b1, w2, b2,
                                         g2, be2, m2, v2, w3, b3, out);
}

// Round 2
// 10045.765 us; speedup vs baseline: 1.2116x; 1.2116x over previous
//
#include <hip/hip_runtime.h>
#include <cstdint>
#include <cstddef>

#define T_LEN 2048
#define BATCH 128

__device__ __forceinline__ float bcast(float v, int l) {
  return __uint_as_float(__builtin_amdgcn_readlane(__float_as_uint(v), (unsigned)l));
}
__device__ __forceinline__ float sigm(float x) {
  return __builtin_amdgcn_rcpf(1.0f + exp2f(-1.4426950408889634f * x));
}
__device__ __forceinline__ float tanh_fast(float x) {
  return 1.0f - 2.0f * __builtin_amdgcn_rcpf(1.0f + exp2f(2.8853900817779268f * x));
}

// lgkm-only fence + raw barrier: LDS writes visible across waves, but vmcnt
// (global prefetch loads, h-stores) stays in flight across the barrier.
#define BAR()                                              \
  do {                                                     \
    asm volatile("s_waitcnt lgkmcnt(0)" ::: "memory");     \
    __builtin_amdgcn_s_barrier();                          \
  } while (0)

// ---------------- proj: in0[t*B+b, j] = relu(x[b,t,:] . w_proj[j,:] + b_proj[j])
__global__ __launch_bounds__(256) void proj_kernel(
    const float* __restrict__ x, const float* __restrict__ w_proj,
    const float* __restrict__ b_proj, float* __restrict__ in0) {
  int R = blockIdx.x * 4 + (threadIdx.x >> 6);  // R = t*BATCH + b
  int j = threadIdx.x & 63;
  int t = R >> 7;
  int b = R & 127;
  const float* xr = x + ((size_t)b * T_LEN + t) * 32;
  const float* wr = w_proj + j * 32;
  float a = b_proj[j];
#pragma unroll
  for (int k = 0; k < 32; ++k) a = fmaf(xr[k], wr[k], a);
  in0[(size_t)R * 64 + j] = fmaxf(a, 0.f);
}

// ---------------- persistent bidirectional LSTM layer, producer/consumer waves
// block = (batch b, direction dir); 512 threads = 8 waves.
// waves 0-3 (tid<256): consumer, thread owns gate-row g=tid, w_hh row in regs.
// waves 4-7: producer, thread owns gate-row g=tid-256, w_ih row in regs,
//            computes pre[t,g] = bias[g] + w_ih[g,:].x[t,:] LEAD steps ahead.
template <int DIN>
__global__ __attribute__((amdgpu_flat_work_group_size(512, 512),
                          amdgpu_waves_per_eu(2, 2)))
void lstm_kernel(
    const float* __restrict__ in,    // [T, B, DIN]
    float* __restrict__ out,         // [T, B, 128] (dir0 -> [0:64), dir1 -> [64:128))
    const float* __restrict__ w_ih,  // [2, 256, DIN]
    const float* __restrict__ w_hh,  // [2, 256, 64]
    const float* __restrict__ bias)  // [2, 256]
{
  const int tid = threadIdx.x;
  const int dir = blockIdx.x & 1;
  const int b = blockIdx.x >> 1;
  const bool is_prod = tid >= 256;
  const int g = is_prod ? (tid - 256) : tid;
  const int j = tid & 63;
  const int LEAD = 8;

  __shared__ float xring[32][DIN];  // input rows (traversal order), 32-slot ring
  __shared__ float pre[32][256];    // pre-activation ring, written LEAD ahead
  __shared__ float zb[2][256];      // z exchange, double buffered

  float4 wih[DIN / 4];  // live only in producer branch
  float4 whh[16];       // live only in consumer branch
  float bz = 0.f;
  if (is_prod) {
    const float4* p = (const float4*)(w_ih + (size_t)(dir * 256 + g) * DIN);
#pragma unroll
    for (int k = 0; k < DIN / 4; ++k) wih[k] = p[k];
    bz = bias[dir * 256 + g];
  } else {
    const float4* p = (const float4*)(w_hh + (size_t)(dir * 256 + g) * 64);
#pragma unroll
    for (int k = 0; k < 16; ++k) whh[k] = p[k];
  }

  // initial x-ring fill: rows 0..31 (traversal order), all 512 threads
#pragma unroll
  for (int q = 0; q < (32 * DIN) / 512; ++q) {
    int idx = tid + 512 * q;
    int r = idx / DIN;
    int col = idx % DIN;
    int t = dir ? (T_LEN - 1 - r) : r;
    xring[r][col] = in[((size_t)t * BATCH + b) * DIN + col];
  }
  __syncthreads();

  float c = 0.f, h = 0.f;
  const int SREG = (16 * DIN) / 256;
  float stg[SREG];

  for (int i = 0; i < T_LEN + LEAD; ++i) {
    if (is_prod) {
      if (i < T_LEN) {
        // refill ISSUE: rows i+16..i+31 into regs (written to LDS 8 iters later)
        if ((i & 15) == 0 && i > 0 && i + 16 < T_LEN) {
#pragma unroll
          for (int q = 0; q < SREG; ++q) {
            int idx = g + 256 * q;
            int r = i + 16 + idx / DIN;
            int col = idx % DIN;
            int t = dir ? (T_LEN - 1 - r) : r;
            stg[q] = in[((size_t)t * BATCH + b) * DIN + col];
          }
        }
        // produce pre[i]: broadcast ds_read_b128 of x row, lane-private weights
        const float4* xr = (const float4*)&xring[i & 31][0];
        float p0 = bz, p1 = 0.f, p2 = 0.f, p3 = 0.f;
#pragma unroll
        for (int k = 0; k < DIN / 4; ++k) {
          float4 xv = xr[k];
          p0 = fmaf(xv.x, wih[k].x, p0);
          p1 = fmaf(xv.y, wih[k].y, p1);
          p2 = fmaf(xv.z, wih[k].z, p2);
          p3 = fmaf(xv.w, wih[k].w, p3);
        }
        pre[i & 31][g] = (p0 + p1) + (p2 + p3);
        // refill WRITE: loads from iteration i-8 have long arrived
        if ((i & 15) == 8 && i > 8 && (i - 8) + 16 < T_LEN) {
#pragma unroll
          for (int q = 0; q < SREG; ++q) {
            int idx = g + 256 * q;
            int r = (i - 8) + 16 + idx / DIN;
            int col = idx % DIN;
            xring[r & 31][col] = stg[q];
          }
        }
      }
    } else {
      int s = i - LEAD;
      if (s >= 0) {
        if (s > 0) {
          // gates of step s-1 from zb, then h-store (no vmcnt drain at barrier)
          float zi = zb[(s - 1) & 1][j];
          float zf = zb[(s - 1) & 1][64 + j];
          float zg = zb[(s - 1) & 1][128 + j];
          float zo = zb[(s - 1) & 1][192 + j];
          float ig = sigm(zi), fg = sigm(zf), gg = tanh_fast(zg), og = sigm(zo);
          c = fmaf(fg, c, ig * gg);
          h = og * tanh_fast(c);
          if (tid < 64) {
            int tp = dir ? (T_LEN - s) : (s - 1);
            out[((size_t)tp * BATCH + b) * 128 + dir * 64 + j] = h;
          }
        }
        // z[g] = pre[s][g] + w_hh[g,:].h  (readlane broadcast, 4 accumulators)
        float a0 = 0.f, a1 = 0.f, a2 = 0.f, a3 = 0.f;
#pragma unroll
        for (int k = 0; k < 16; ++k) {
          a0 = fmaf(bcast(h, 4 * k), whh[k].x, a0);
          a1 = fmaf(bcast(h, 4 * k + 1), whh[k].y, a1);
          a2 = fmaf(bcast(h, 4 * k + 2), whh[k].z, a2);
          a3 = fmaf(bcast(h, 4 * k + 3), whh[k].w, a3);
        }
        zb[s & 1][g] = pre[s & 31][g] + ((a0 + a1) + (a2 + a3));
      }
    }
    BAR();
  }

  // epilogue: gates of final step s=T-1 (consumer wave 0 only)
  if (tid < 64) {
    const int pb = (T_LEN - 1) & 1;
    float zi = zb[pb][j];
    float zf = zb[pb][64 + j];
    float zg = zb[pb][128 + j];
    float zo = zb[pb][192 + j];
    float ig = sigm(zi), fg = sigm(zf), gg = tanh_fast(zg), og = sigm(zo);
    c = fmaf(fg, c, ig * gg);
    h = og * tanh_fast(c);
    int tp = dir ? 0 : (T_LEN - 1);
    out[((size_t)tp * BATCH + b) * 128 + dir * 64 + j] = h;
  }
}

// ---------------- attention: scores + softmax + pooled, one block per batch row
__global__ __launch_bounds__(256) void attn_kernel(
    const float* __restrict__ hs,      // [T, B, 128]
    const float* __restrict__ w_attn,  // [128]
    float* __restrict__ pooled)        // [B, 128]
{
  const int b = blockIdx.x, tid = threadIdx.x;
  __shared__ float wa[128];
  __shared__ float sc[T_LEN];
  __shared__ float red[256];
  if (tid < 128) wa[tid] = w_attn[tid];
  __syncthreads();

  float lmax = -3.4e38f;
#pragma unroll
  for (int i = 0; i < T_LEN / 256; ++i) {
    int t = tid + 256 * i;
    const float4* r4 = (const float4*)(hs + ((size_t)t * BATCH + b) * 128);
    float s = 0.f;
#pragma unroll
    for (int k = 0; k < 32; ++k) {
      float4 v = r4[k];
      s += v.x * wa[4 * k] + v.y * wa[4 * k + 1] + v.z * wa[4 * k + 2] + v.w * wa[4 * k + 3];
    }
    sc[t] = s;
    lmax = fmaxf(lmax, s);
  }
  red[tid] = lmax;
  __syncthreads();
  for (int off = 128; off > 0; off >>= 1) {
    if (tid < off) red[tid] = fmaxf(red[tid], red[tid + off]);
    __syncthreads();
  }
  float m = red[0];
  __syncthreads();

  float lsum = 0.f;
#pragma unroll
  for (int i = 0; i < T_LEN / 256; ++i) {
    int t = tid + 256 * i;
    float e = exp2f((sc[t] - m) * 1.4426950408889634f);
    sc[t] = e;
    lsum += e;
  }
  red[tid] = lsum;
  __syncthreads();
  for (int off = 128; off > 0; off >>= 1) {
    if (tid < off) red[tid] += red[tid + off];
    __syncthreads();
  }
  float inv = __builtin_amdgcn_rcpf(red[0]);

  if (tid < 128) {
    float a0 = 0.f, a1 = 0.f, a2 = 0.f, a3 = 0.f;
    for (int t = 0; t < T_LEN; t += 4) {
      a0 = fmaf(sc[t], hs[((size_t)t * BATCH + b) * 128 + tid], a0);
      a1 = fmaf(sc[t + 1], hs[((size_t)(t + 1) * BATCH + b) * 128 + tid], a1);
      a2 = fmaf(sc[t + 2], hs[((size_t)(t + 2) * BATCH + b) * 128 + tid], a2);
      a3 = fmaf(sc[t + 3], hs[((size_t)(t + 3) * BATCH + b) * 128 + tid], a3);
    }
    pooled[b * 128 + tid] = ((a0 + a1) + (a2 + a3)) * inv;
  }
}

// ---------------- head: BN1 -> fc1 -> relu -> fc2 -> elu -> BN2 -> fc3
__global__ __launch_bounds__(128) void head_kernel(
    const float* __restrict__ pooled,
    const float* g1, const float* be1, const float* m1, const float* v1,
    const float* w1, const float* b1, const float* w2, const float* b2,
    const float* g2, const float* be2, const float* m2, const float* v2,
    const float* w3, const float* b3, float* __restrict__ out) {
  const int b = blockIdx.x, tid = threadIdx.x;
  __shared__ float xb[128], y1[128], y2[64];
  xb[tid] = (pooled[b * 128 + tid] - m1[tid]) * rsqrtf(v1[tid] + 1e-5f) * g1[tid] + be1[tid];
  __syncthreads();
  float a = b1[tid];
#pragma unroll 8
  for (int k = 0; k < 128; ++k) a = fmaf(xb[k], w1[tid * 128 + k], a);
  y1[tid] = fmaxf(a, 0.f);
  __syncthreads();
  if (tid < 64) {
    float a2 = b2[tid];
#pragma unroll 8
    for (int k = 0; k < 128; ++k) a2 = fmaf(y1[k], w2[tid * 128 + k], a2);
    if (a2 < 0.f) a2 = exp2f(a2 * 1.4426950408889634f) - 1.0f;  // elu
    y2[tid] = (a2 - m2[tid]) * rsqrtf(v2[tid] + 1e-5f) * g2[tid] + be2[tid];
  }
  __syncthreads();
  if (tid < 3) {
    float a3 = b3[tid];
#pragma unroll
    for (int k = 0; k < 64; ++k) a3 = fmaf(y2[k], w3[tid * 64 + k], a3);
    out[b * 3 + tid] = a3;
  }
}

extern "C" void kernel_launch(void* const* d_in, const int* in_sizes, int n_in,
                              void* d_out, int out_size, void* d_ws, size_t ws_size,
                              hipStream_t stream) {
  const float* x      = (const float*)d_in[0];
  const float* w_proj = (const float*)d_in[1];
  const float* b_proj = (const float*)d_in[2];
  const float* w_ih_l0 = (const float*)d_in[3];
  const float* w_hh_l0 = (const float*)d_in[4];
  const float* b_l0    = (const float*)d_in[5];
  const float* w_ih_r  = (const float*)d_in[6];  // [3,2,256,128]
  const float* w_hh_r  = (const float*)d_in[7];  // [3,2,256,64]
  const float* b_r     = (const float*)d_in[8];  // [3,2,256]
  const float* w_attn  = (const float*)d_in[9];
  const float* g1  = (const float*)d_in[11];
  const float* be1 = (const float*)d_in[12];
  const float* m1  = (const float*)d_in[13];
  const float* v1  = (const float*)d_in[14];
  const float* w1  = (const float*)d_in[15];
  const float* b1  = (const float*)d_in[16];
  const float* w2  = (const float*)d_in[17];
  const float* b2  = (const float*)d_in[18];
  const float* g2  = (const float*)d_in[19];
  const float* be2 = (const float*)d_in[20];
  const float* m2  = (const float*)d_in[21];
  const float* v2  = (const float*)d_in[22];
  const float* w3  = (const float*)d_in[23];
  const float* b3  = (const float*)d_in[24];
  float* out = (float*)d_out;

  // ws layout: bufA [T,B,128] | bufB [T,B,128]  (in0 and pooled overlay dead regions)
  float* bufA = (float*)d_ws;
  float* bufB = bufA + (size_t)T_LEN * BATCH * 128;
  float* in0 = bufB;     // [T,B,64]; dead once layer1 starts writing bufB
  float* pooled = bufA;  // reused after layer3 no longer reads bufA

  proj_kernel<<<T_LEN * BATCH / 4, 256, 0, stream>>>(x, w_proj, b_proj, in0);
  lstm_kernel<64><<<256, 512, 0, stream>>>(in0, bufA, w_ih_l0, w_hh_l0, b_l0);
  lstm_kernel<128><<<256, 512, 0, stream>>>(bufA, bufB, w_ih_r, w_hh_r, b_r);
  lstm_kernel<128><<<256, 512, 0, stream>>>(bufB, bufA, w_ih_r + 65536, w_hh_r + 32768, b_r + 512);
  lstm_kernel<128><<<256, 512, 0, stream>>>(bufA, bufB, w_ih_r + 131072, w_hh_r + 65536, b_r + 1024);
  attn_kernel<<<BATCH, 256, 0, stream>>>(bufB, w_attn, pooled);
  head_kernel<<<BATCH, 128, 0, stream>>>(pooled, g1, be1, m1, v1, w1, b1, w2, b2,
                                         g2, be2, m2, v2, w3, b3, out);
}

// Round 3
// 9432.462 us; speedup vs baseline: 1.2904x; 1.0650x over previous
//
#include <hip/hip_runtime.h>
#include <cstdint>
#include <cstddef>

#define T_LEN 2048
#define BATCH 128

__device__ __forceinline__ float bcast(float v, int l) {
  return __uint_as_float(__builtin_amdgcn_readlane(__float_as_uint(v), (unsigned)l));
}
__device__ __forceinline__ float sigm(float x) {
  return __builtin_amdgcn_rcpf(1.0f + exp2f(-1.4426950408889634f * x));
}
__device__ __forceinline__ float tanh_fast(float x) {
  return 1.0f - 2.0f * __builtin_amdgcn_rcpf(1.0f + exp2f(2.8853900817779268f * x));
}

// lgkm-only fence + raw barrier: LDS writes visible across waves, but vmcnt
// (global prefetch loads, h-stores) stays in flight across the barrier.
#define BAR()                                              \
  do {                                                     \
    asm volatile("s_waitcnt lgkmcnt(0)" ::: "memory");     \
    __builtin_amdgcn_s_barrier();                          \
    asm volatile("" ::: "memory");                         \
  } while (0)

// ---------------- proj: in0[t*B+b, j] = relu(x[b,t,:] . w_proj[j,:] + b_proj[j])
__global__ __launch_bounds__(256) void proj_kernel(
    const float* __restrict__ x, const float* __restrict__ w_proj,
    const float* __restrict__ b_proj, float* __restrict__ in0) {
  int R = blockIdx.x * 4 + (threadIdx.x >> 6);  // R = t*BATCH + b
  int j = threadIdx.x & 63;
  int t = R >> 7;
  int b = R & 127;
  const float* xr = x + ((size_t)b * T_LEN + t) * 32;
  const float* wr = w_proj + j * 32;
  float a = b_proj[j];
#pragma unroll
  for (int k = 0; k < 32; ++k) a = fmaf(xr[k], wr[k], a);
  in0[(size_t)R * 64 + j] = fmaxf(a, 0.f);
}

// ---------------- persistent bidirectional LSTM layer, producer/consumer waves
// block = (batch b, direction dir); 768 threads = 12 waves.
// waves 0-3  (tid<256):      consumer; thread owns gate-row g=tid, full w_hh row
//                            (16 float4) in regs, runs the serial recurrence.
// waves 4-11 (tid 256..767): producer; thread owns HALF of w_ih row g,
//                            g = ptid&255, half = ptid>>8 (<=16 float4 in regs),
//                            computes preh[t][half][g] LEAD steps ahead.
// Key: ONE shared register array w[16] for both branches -> union cost 64 VGPR.
template <int DIN>
__global__ __attribute__((amdgpu_flat_work_group_size(768, 768),
                          amdgpu_waves_per_eu(3)))
void lstm_kernel(
    const float* __restrict__ in,    // [T, B, DIN]
    float* __restrict__ out,         // [T, B, 128] (dir0 -> [0:64), dir1 -> [64:128))
    const float* __restrict__ w_ih,  // [2, 256, DIN]
    const float* __restrict__ w_hh,  // [2, 256, 64]
    const float* __restrict__ bias)  // [2, 256]
{
  constexpr int DH = DIN / 2;           // floats per producer half-row
  constexpr int NF4 = DH / 4;           // float4 per producer half-row (8 or 16)
  constexpr int SREG = 16 * DIN / 512;  // refill elems per producer thread (2/4)
  constexpr int IREG = 32 * DIN / 512;  // initial-fill elems per producer (4/8)
  const int LEAD = 8;

  const int tid = threadIdx.x;
  const int dir = blockIdx.x & 1;
  const int b = blockIdx.x >> 1;
  const bool is_prod = tid >= 256;
  const int ptid = tid - 256;                 // producer index 0..511
  const int g = is_prod ? (ptid & 255) : tid; // gate row this thread serves
  const int half = is_prod ? (ptid >> 8) : 0; // producer half (wave-uniform)
  const int j = tid & 63;

  __shared__ float xring[32][DIN];     // input rows (traversal order), ring
  __shared__ float preh[16][2][256];   // pre-activation halves, ring (LEAD ahead)
  __shared__ float zb[2][256];         // z exchange, double buffered

  // ---- ONE register array, loaded per-branch (shared storage!)
  float4 w[16];
  float bz = 0.f;
  if (is_prod) {
    const float4* p = (const float4*)(w_ih + (size_t)(dir * 256 + g) * DIN + half * DH);
#pragma unroll
    for (int k = 0; k < NF4; ++k) w[k] = p[k];
    if (half == 0) bz = bias[dir * 256 + g];
  } else {
    const float4* p = (const float4*)(w_hh + (size_t)(dir * 256 + g) * 64);
#pragma unroll
    for (int k = 0; k < 16; ++k) w[k] = p[k];
  }

  // ---- initial x-ring fill: rows 0..31 in traversal order (producers only)
  if (is_prod) {
#pragma unroll
    for (int q = 0; q < IREG; ++q) {
      int idx = ptid + 512 * q;
      int r = idx / DIN;
      int col = idx % DIN;
      int t = dir ? (T_LEN - 1 - r) : r;
      xring[r][col] = in[((size_t)t * BATCH + b) * DIN + col];
    }
  }
  __syncthreads();

  float c = 0.f, h = 0.f;
  float stg[SREG];

  for (int i = 0; i < T_LEN + LEAD; ++i) {
    if (is_prod) {
      if (i < T_LEN) {
        // refill ISSUE: rows i+16..i+31 into regs (LDS-written 8 iters later)
        if ((i & 15) == 0 && i > 0 && i + 16 < T_LEN) {
#pragma unroll
          for (int q = 0; q < SREG; ++q) {
            int idx = ptid + 512 * q;
            int r = i + 16 + idx / DIN;
            int col = idx % DIN;
            int t = dir ? (T_LEN - 1 - r) : r;
            stg[q] = in[((size_t)t * BATCH + b) * DIN + col];
          }
        }
        // produce preh[i][half]: broadcast ds_read_b128 of x half-row
        const float4* xr = (const float4*)&xring[i & 31][half * DH];
        float p0 = bz, p1 = 0.f, p2 = 0.f, p3 = 0.f;
#pragma unroll
        for (int k = 0; k < NF4; ++k) {
          float4 xv = xr[k];
          p0 = fmaf(xv.x, w[k].x, p0);
          p1 = fmaf(xv.y, w[k].y, p1);
          p2 = fmaf(xv.z, w[k].z, p2);
          p3 = fmaf(xv.w, w[k].w, p3);
        }
        preh[i & 15][half][g] = (p0 + p1) + (p2 + p3);
        // refill WRITE: loads issued at i-8 have arrived (~3000 cy of slack)
        if ((i & 15) == 8 && i > 8 && (i - 8) + 16 < T_LEN) {
#pragma unroll
          for (int q = 0; q < SREG; ++q) {
            int idx = ptid + 512 * q;
            int r = (i - 8) + 16 + idx / DIN;
            int col = idx % DIN;
            xring[r & 31][col] = stg[q];
          }
        }
      }
    } else {
      int s = i - LEAD;
      if (s >= 0) {
        if (s > 0) {
          // gates of step s-1 from zb; h-store stays in flight across barrier
          float zi = zb[(s - 1) & 1][j];
          float zf = zb[(s - 1) & 1][64 + j];
          float zg = zb[(s - 1) & 1][128 + j];
          float zo = zb[(s - 1) & 1][192 + j];
          float ig = sigm(zi), fg = sigm(zf), gg = tanh_fast(zg), og = sigm(zo);
          c = fmaf(fg, c, ig * gg);
          h = og * tanh_fast(c);
          if (tid < 64) {
            int tp = dir ? (T_LEN - s) : (s - 1);
            out[((size_t)tp * BATCH + b) * 128 + dir * 64 + j] = h;
          }
        }
        float pr0 = preh[s & 15][0][g];
        float pr1 = preh[s & 15][1][g];
        // z[g] = pre + w_hh[g,:].h  (readlane broadcast, 4 accumulators)
        float a0 = 0.f, a1 = 0.f, a2 = 0.f, a3 = 0.f;
#pragma unroll
        for (int k = 0; k < 16; ++k) {
          a0 = fmaf(bcast(h, 4 * k), w[k].x, a0);
          a1 = fmaf(bcast(h, 4 * k + 1), w[k].y, a1);
          a2 = fmaf(bcast(h, 4 * k + 2), w[k].z, a2);
          a3 = fmaf(bcast(h, 4 * k + 3), w[k].w, a3);
        }
        zb[s & 1][g] = (pr0 + pr1) + ((a0 + a1) + (a2 + a3));
      }
    }
    BAR();
  }

  // epilogue: gates of final step s=T-1 (consumer wave 0 only)
  if (tid < 64) {
    const int pb = (T_LEN - 1) & 1;
    float zi = zb[pb][j];
    float zf = zb[pb][64 + j];
    float zg = zb[pb][128 + j];
    float zo = zb[pb][192 + j];
    float ig = sigm(zi), fg = sigm(zf), gg = tanh_fast(zg), og = sigm(zo);
    c = fmaf(fg, c, ig * gg);
    h = og * tanh_fast(c);
    int tp = dir ? 0 : (T_LEN - 1);
    out[((size_t)tp * BATCH + b) * 128 + dir * 64 + j] = h;
  }
}

// ---------------- attention: scores + softmax + pooled, one block per batch row
__global__ __launch_bounds__(256) void attn_kernel(
    const float* __restrict__ hs,      // [T, B, 128]
    const float* __restrict__ w_attn,  // [128]
    float* __restrict__ pooled)        // [B, 128]
{
  const int b = blockIdx.x, tid = threadIdx.x;
  __shared__ float wa[128];
  __shared__ float sc[T_LEN];
  __shared__ float red[256];
  if (tid < 128) wa[tid] = w_attn[tid];
  __syncthreads();

  float lmax = -3.4e38f;
#pragma unroll
  for (int i = 0; i < T_LEN / 256; ++i) {
    int t = tid + 256 * i;
    const float4* r4 = (const float4*)(hs + ((size_t)t * BATCH + b) * 128);
    float s = 0.f;
#pragma unroll
    for (int k = 0; k < 32; ++k) {
      float4 v = r4[k];
      s += v.x * wa[4 * k] + v.y * wa[4 * k + 1] + v.z * wa[4 * k + 2] + v.w * wa[4 * k + 3];
    }
    sc[t] = s;
    lmax = fmaxf(lmax, s);
  }
  red[tid] = lmax;
  __syncthreads();
  for (int off = 128; off > 0; off >>= 1) {
    if (tid < off) red[tid] = fmaxf(red[tid], red[tid + off]);
    __syncthreads();
  }
  float m = red[0];
  __syncthreads();

  float lsum = 0.f;
#pragma unroll
  for (int i = 0; i < T_LEN / 256; ++i) {
    int t = tid + 256 * i;
    float e = exp2f((sc[t] - m) * 1.4426950408889634f);
    sc[t] = e;
    lsum += e;
  }
  red[tid] = lsum;
  __syncthreads();
  for (int off = 128; off > 0; off >>= 1) {
    if (tid < off) red[tid] += red[tid + off];
    __syncthreads();
  }
  float inv = __builtin_amdgcn_rcpf(red[0]);

  if (tid < 128) {
    float a0 = 0.f, a1 = 0.f, a2 = 0.f, a3 = 0.f;
    for (int t = 0; t < T_LEN; t += 4) {
      a0 = fmaf(sc[t], hs[((size_t)t * BATCH + b) * 128 + tid], a0);
      a1 = fmaf(sc[t + 1], hs[((size_t)(t + 1) * BATCH + b) * 128 + tid], a1);
      a2 = fmaf(sc[t + 2], hs[((size_t)(t + 2) * BATCH + b) * 128 + tid], a2);
      a3 = fmaf(sc[t + 3], hs[((size_t)(t + 3) * BATCH + b) * 128 + tid], a3);
    }
    pooled[b * 128 + tid] = ((a0 + a1) + (a2 + a3)) * inv;
  }
}

// ---------------- head: BN1 -> fc1 -> relu -> fc2 -> elu -> BN2 -> fc3
__global__ __launch_bounds__(128) void head_kernel(
    const float* __restrict__ pooled,
    const float* g1, const float* be1, const float* m1, const float* v1,
    const float* w1, const float* b1, const float* w2, const float* b2,
    const float* g2, const float* be2, const float* m2, const float* v2,
    const float* w3, const float* b3, float* __restrict__ out) {
  const int b = blockIdx.x, tid = threadIdx.x;
  __shared__ float xb[128], y1[128], y2[64];
  xb[tid] = (pooled[b * 128 + tid] - m1[tid]) * rsqrtf(v1[tid] + 1e-5f) * g1[tid] + be1[tid];
  __syncthreads();
  float a = b1[tid];
#pragma unroll 8
  for (int k = 0; k < 128; ++k) a = fmaf(xb[k], w1[tid * 128 + k], a);
  y1[tid] = fmaxf(a, 0.f);
  __syncthreads();
  if (tid < 64) {
    float a2 = b2[tid];
#pragma unroll 8
    for (int k = 0; k < 128; ++k) a2 = fmaf(y1[k], w2[tid * 128 + k], a2);
    if (a2 < 0.f) a2 = exp2f(a2 * 1.4426950408889634f) - 1.0f;  // elu
    y2[tid] = (a2 - m2[tid]) * rsqrtf(v2[tid] + 1e-5f) * g2[tid] + be2[tid];
  }
  __syncthreads();
  if (tid < 3) {
    float a3 = b3[tid];
#pragma unroll
    for (int k = 0; k < 64; ++k) a3 = fmaf(y2[k], w3[tid * 64 + k], a3);
    out[b * 3 + tid] = a3;
  }
}

extern "C" void kernel_launch(void* const* d_in, const int* in_sizes, int n_in,
                              void* d_out, int out_size, void* d_ws, size_t ws_size,
                              hipStream_t stream) {
  const float* x      = (const float*)d_in[0];
  const float* w_proj = (const float*)d_in[1];
  const float* b_proj = (const float*)d_in[2];
  const float* w_ih_l0 = (const float*)d_in[3];
  const float* w_hh_l0 = (const float*)d_in[4];
  const float* b_l0    = (const float*)d_in[5];
  const float* w_ih_r  = (const float*)d_in[6];  // [3,2,256,128]
  const float* w_hh_r  = (const float*)d_in[7];  // [3,2,256,64]
  const float* b_r     = (const float*)d_in[8];  // [3,2,256]
  const float* w_attn  = (const float*)d_in[9];
  const float* g1  = (const float*)d_in[11];
  const float* be1 = (const float*)d_in[12];
  const float* m1  = (const float*)d_in[13];
  const float* v1  = (const float*)d_in[14];
  const float* w1  = (const float*)d_in[15];
  const float* b1  = (const float*)d_in[16];
  const float* w2  = (const float*)d_in[17];
  const float* b2  = (const float*)d_in[18];
  const float* g2  = (const float*)d_in[19];
  const float* be2 = (const float*)d_in[20];
  const float* m2  = (const float*)d_in[21];
  const float* v2  = (const float*)d_in[22];
  const float* w3  = (const float*)d_in[23];
  const float* b3  = (const float*)d_in[24];
  float* out = (float*)d_out;

  // ws layout: bufA [T,B,128] | bufB [T,B,128]  (in0 and pooled overlay dead regions)
  float* bufA = (float*)d_ws;
  float* bufB = bufA + (size_t)T_LEN * BATCH * 128;
  float* in0 = bufB;     // [T,B,64]; dead once layer1 starts writing bufB
  float* pooled = bufA;  // reused after layer3 no longer reads bufA

  proj_kernel<<<T_LEN * BATCH / 4, 256, 0, stream>>>(x, w_proj, b_proj, in0);
  lstm_kernel<64><<<256, 768, 0, stream>>>(in0, bufA, w_ih_l0, w_hh_l0, b_l0);
  lstm_kernel<128><<<256, 768, 0, stream>>>(bufA, bufB, w_ih_r, w_hh_r, b_r);
  lstm_kernel<128><<<256, 768, 0, stream>>>(bufB, bufA, w_ih_r + 65536, w_hh_r + 32768, b_r + 512);
  lstm_kernel<128><<<256, 768, 0, stream>>>(bufA, bufB, w_ih_r + 131072, w_hh_r + 65536, b_r + 1024);
  attn_kernel<<<BATCH, 256, 0, stream>>>(bufB, w_attn, pooled);
  head_kernel<<<BATCH, 128, 0, stream>>>(pooled, g1, be1, m1, v1, w1, b1, w2, b2,
                                         g2, be2, m2, v2, w3, b3, out);
}

// Round 4
// 9184.332 us; speedup vs baseline: 1.3253x; 1.0270x over previous
//
#include <hip/hip_runtime.h>
#include <cstdint>
#include <cstddef>

#define T_LEN 2048
#define BATCH 128

__device__ __forceinline__ float bcast(float v, int l) {
  return __uint_as_float(__builtin_amdgcn_readlane(__float_as_uint(v), (unsigned)l));
}
__device__ __forceinline__ float sigm(float x) {
  return __builtin_amdgcn_rcpf(1.0f + exp2f(-1.4426950408889634f * x));
}
__device__ __forceinline__ float tanh_fast(float x) {
  return 1.0f - 2.0f * __builtin_amdgcn_rcpf(1.0f + exp2f(2.8853900817779268f * x));
}

// lgkm-only fence + raw barrier: LDS writes visible across waves, but vmcnt
// (global prefetch loads, h-stores) stays in flight across the barrier.
#define BAR()                                              \
  do {                                                     \
    asm volatile("s_waitcnt lgkmcnt(0)" ::: "memory");     \
    __builtin_amdgcn_s_barrier();                          \
    asm volatile("" ::: "memory");                         \
  } while (0)

// ---------------- proj: in0[t*B+b, j] = relu(x[b,t,:] . w_proj[j,:] + b_proj[j])
__global__ __launch_bounds__(256) void proj_kernel(
    const float* __restrict__ x, const float* __restrict__ w_proj,
    const float* __restrict__ b_proj, float* __restrict__ in0) {
  int R = blockIdx.x * 4 + (threadIdx.x >> 6);  // R = t*BATCH + b
  int j = threadIdx.x & 63;
  int t = R >> 7;
  int b = R & 127;
  const float* xr = x + ((size_t)b * T_LEN + t) * 32;
  const float* wr = w_proj + j * 32;
  float a = b_proj[j];
#pragma unroll
  for (int k = 0; k < 32; ++k) a = fmaf(xr[k], wr[k], a);
  in0[(size_t)R * 64 + j] = fmaxf(a, 0.f);
}

// ---------------- persistent bidirectional LSTM layer, producer/consumer waves
// block = (batch b, direction dir); 768 threads = 12 waves.
// waves 0-3  (tid<256):  consumer; thread owns gate-row g=tid, full w_hh row
//                        (16 float4) in regs, runs the serial recurrence.
// waves 4-11 (ptid<512): producer wave pw = ptid>>6 = (og | ks<<1):
//                        og in {0,1}: output half (128 gates, 2 per lane),
//                        ks in {0..3}: K-slice of width KW=DIN/4.
//                        x delivered via readlane from lane-sliced VGPRs (NOT
//                        LDS broadcast -> kills the 131 KB/step LDS drain).
// ONE shared register array w[16] for both branches -> union cost 64 VGPR.
template <int DIN>
__global__ __attribute__((amdgpu_flat_work_group_size(768, 768),
                          amdgpu_waves_per_eu(3)))
void lstm_kernel(
    const float* __restrict__ in,    // [T, B, DIN]
    float* __restrict__ out,         // [T, B, 128] (dir0 -> [0:64), dir1 -> [64:128))
    const float* __restrict__ w_ih,  // [2, 256, DIN]
    const float* __restrict__ w_hh,  // [2, 256, 64]
    const float* __restrict__ bias)  // [2, 256]
{
  constexpr int KW = DIN / 4;           // K per producer wave (32 / 16)
  constexpr int NF4W = KW / 4;          // float4 per row-slice (8 / 4)
  constexpr int SREG = 16 * DIN / 512;  // refill elems per producer thread (4/2)
  constexpr int IREG = 32 * DIN / 512;  // initial-fill elems per producer (8/4)
  const int LEAD = 4;

  const int tid = threadIdx.x;
  const int dir = blockIdx.x & 1;
  const int b = blockIdx.x >> 1;
  const bool is_prod = tid >= 256;
  const int ptid = tid - 256;    // producer index 0..511
  const int pw = ptid >> 6;      // producer wave 0..7
  const int og = pw & 1;         // output half
  const int ks = pw >> 1;        // K-slice
  const int l = tid & 63;        // lane
  const int g = tid;             // consumer gate row

  __shared__ float xring[32][DIN];    // input rows (traversal order), ring
  __shared__ float preh[8][4][256];   // partial pre-activations [slot][ks][g]
  __shared__ float zb[2][256];        // z exchange, double buffered

  // ---- ONE register array, loaded per-branch (shared storage!)
  float4 w[16];
  float bz = 0.f;
  if (is_prod) {
    // rows g0 = og*128+l and g1 = og*128+64+l, cols [KW*ks, KW*ks+KW)
    const float4* r0 = (const float4*)(w_ih + (size_t)(dir * 256 + og * 128 + l) * DIN + KW * ks);
    const float4* r1 = (const float4*)(w_ih + (size_t)(dir * 256 + og * 128 + 64 + l) * DIN + KW * ks);
#pragma unroll
    for (int k = 0; k < NF4W; ++k) w[k] = r0[k];
#pragma unroll
    for (int k = 0; k < NF4W; ++k) w[NF4W + k] = r1[k];
  } else {
    const float4* p = (const float4*)(w_hh + (size_t)(dir * 256 + g) * 64);
#pragma unroll
    for (int k = 0; k < 16; ++k) w[k] = p[k];
    bz = bias[dir * 256 + g];
  }

  // ---- initial x-ring fill: rows 0..31 in traversal order (producers only)
  if (is_prod) {
#pragma unroll
    for (int q = 0; q < IREG; ++q) {
      int idx = ptid + 512 * q;
      int r = idx / DIN;
      int col = idx % DIN;
      int t = dir ? (T_LEN - 1 - r) : r;
      xring[r][col] = in[((size_t)t * BATCH + b) * DIN + col];
    }
  }
  __syncthreads();

  float c = 0.f, h = 0.f;
  float stg[SREG];
  // wave-uniform readlane base for the x slice
  const int rlbase = __builtin_amdgcn_readfirstlane((ks * KW) & 63);
  const bool xhigh = (ks * KW) >= 64;

  for (int i = 0; i < T_LEN + LEAD; ++i) {
    if (is_prod) {
      if (i < T_LEN) {
        // refill ISSUE: rows i+16..i+31 into regs (LDS-written 8 iters later)
        if ((i & 15) == 0 && i > 0 && i + 16 < T_LEN) {
#pragma unroll
          for (int q = 0; q < SREG; ++q) {
            int idx = ptid + 512 * q;
            int r = i + 16 + idx / DIN;
            int col = idx % DIN;
            int t = dir ? (T_LEN - 1 - r) : r;
            stg[q] = in[((size_t)t * BATCH + b) * DIN + col];
          }
        }
        // stage x row lane-sliced (per-lane distinct reads, ~512 B/wave)
        const int slot = i & 31;
        float xv0 = xring[slot][l];
        float xs;
        if constexpr (DIN == 128) {
          float xv1 = xring[slot][64 + l];
          xs = xhigh ? xv1 : xv0;
        } else {
          xs = xv0;
        }
        // partial dots: outputs g0=og*128+l, g1=og*128+64+l over K-slice ks
        const float* wf = (const float*)w;
        float a0 = 0.f, a1 = 0.f;
#pragma unroll
        for (int k = 0; k < KW; ++k) {
          float s = bcast(xs, rlbase + k);
          a0 = fmaf(s, wf[k], a0);
          a1 = fmaf(s, wf[KW + k], a1);
        }
        preh[i & 7][ks][og * 128 + l] = a0;
        preh[i & 7][ks][og * 128 + 64 + l] = a1;
        // refill WRITE: loads issued at i-8 have arrived (~8 steps of slack)
        if ((i & 15) == 8 && i > 8 && (i - 8) + 16 < T_LEN) {
#pragma unroll
          for (int q = 0; q < SREG; ++q) {
            int idx = ptid + 512 * q;
            int r = (i - 8) + 16 + idx / DIN;
            int col = idx % DIN;
            xring[r & 31][col] = stg[q];
          }
        }
      }
    } else {
      int s = i - LEAD;
      if (s >= 0) {
        // prefetch pre partials early (independent of h -> latency hidden)
        float pr0 = preh[s & 7][0][g];
        float pr1 = preh[s & 7][1][g];
        float pr2 = preh[s & 7][2][g];
        float pr3 = preh[s & 7][3][g];
        if (s > 0) {
          // gates of step s-1 from zb; h-store stays in flight across barrier
          float zi = zb[(s - 1) & 1][l];
          float zf = zb[(s - 1) & 1][64 + l];
          float zg = zb[(s - 1) & 1][128 + l];
          float zo = zb[(s - 1) & 1][192 + l];
          float ig = sigm(zi), fg = sigm(zf), gg = tanh_fast(zg), og_ = sigm(zo);
          c = fmaf(fg, c, ig * gg);
          h = og_ * tanh_fast(c);
          if (tid < 64) {
            int tp = dir ? (T_LEN - s) : (s - 1);
            out[((size_t)tp * BATCH + b) * 128 + dir * 64 + l] = h;
          }
        }
        // z[g] = bias + pre + w_hh[g,:].h  (readlane broadcast, 4 accumulators)
        float a0 = 0.f, a1 = 0.f, a2 = 0.f, a3 = 0.f;
#pragma unroll
        for (int k = 0; k < 16; ++k) {
          a0 = fmaf(bcast(h, 4 * k), w[k].x, a0);
          a1 = fmaf(bcast(h, 4 * k + 1), w[k].y, a1);
          a2 = fmaf(bcast(h, 4 * k + 2), w[k].z, a2);
          a3 = fmaf(bcast(h, 4 * k + 3), w[k].w, a3);
        }
        zb[s & 1][g] = (bz + ((pr0 + pr1) + (pr2 + pr3))) + ((a0 + a1) + (a2 + a3));
      }
    }
    BAR();
  }

  // epilogue: gates of final step s=T-1 (consumer wave 0 only)
  if (tid < 64) {
    const int pb = (T_LEN - 1) & 1;
    float zi = zb[pb][l];
    float zf = zb[pb][64 + l];
    float zg = zb[pb][128 + l];
    float zo = zb[pb][192 + l];
    float ig = sigm(zi), fg = sigm(zf), gg = tanh_fast(zg), og_ = sigm(zo);
    c = fmaf(fg, c, ig * gg);
    h = og_ * tanh_fast(c);
    int tp = dir ? 0 : (T_LEN - 1);
    out[((size_t)tp * BATCH + b) * 128 + dir * 64 + l] = h;
  }
}

// ---------------- attention: scores + softmax + pooled, one block per batch row
__global__ __launch_bounds__(256) void attn_kernel(
    const float* __restrict__ hs,      // [T, B, 128]
    const float* __restrict__ w_attn,  // [128]
    float* __restrict__ pooled)        // [B, 128]
{
  const int b = blockIdx.x, tid = threadIdx.x;
  __shared__ float wa[128];
  __shared__ float sc[T_LEN];
  __shared__ float red[256];
  if (tid < 128) wa[tid] = w_attn[tid];
  __syncthreads();

  float lmax = -3.4e38f;
#pragma unroll
  for (int i = 0; i < T_LEN / 256; ++i) {
    int t = tid + 256 * i;
    const float4* r4 = (const float4*)(hs + ((size_t)t * BATCH + b) * 128);
    float s = 0.f;
#pragma unroll
    for (int k = 0; k < 32; ++k) {
      float4 v = r4[k];
      s += v.x * wa[4 * k] + v.y * wa[4 * k + 1] + v.z * wa[4 * k + 2] + v.w * wa[4 * k + 3];
    }
    sc[t] = s;
    lmax = fmaxf(lmax, s);
  }
  red[tid] = lmax;
  __syncthreads();
  for (int off = 128; off > 0; off >>= 1) {
    if (tid < off) red[tid] = fmaxf(red[tid], red[tid + off]);
    __syncthreads();
  }
  float m = red[0];
  __syncthreads();

  float lsum = 0.f;
#pragma unroll
  for (int i = 0; i < T_LEN / 256; ++i) {
    int t = tid + 256 * i;
    float e = exp2f((sc[t] - m) * 1.4426950408889634f);
    sc[t] = e;
    lsum += e;
  }
  red[tid] = lsum;
  __syncthreads();
  for (int off = 128; off > 0; off >>= 1) {
    if (tid < off) red[tid] += red[tid + off];
    __syncthreads();
  }
  float inv = __builtin_amdgcn_rcpf(red[0]);

  if (tid < 128) {
    float a0 = 0.f, a1 = 0.f, a2 = 0.f, a3 = 0.f;
    for (int t = 0; t < T_LEN; t += 4) {
      a0 = fmaf(sc[t], hs[((size_t)t * BATCH + b) * 128 + tid], a0);
      a1 = fmaf(sc[t + 1], hs[((size_t)(t + 1) * BATCH + b) * 128 + tid], a1);
      a2 = fmaf(sc[t + 2], hs[((size_t)(t + 2) * BATCH + b) * 128 + tid], a2);
      a3 = fmaf(sc[t + 3], hs[((size_t)(t + 3) * BATCH + b) * 128 + tid], a3);
    }
    pooled[b * 128 + tid] = ((a0 + a1) + (a2 + a3)) * inv;
  }
}

// ---------------- head: BN1 -> fc1 -> relu -> fc2 -> elu -> BN2 -> fc3
__global__ __launch_bounds__(128) void head_kernel(
    const float* __restrict__ pooled,
    const float* g1, const float* be1, const float* m1, const float* v1,
    const float* w1, const float* b1, const float* w2, const float* b2,
    const float* g2, const float* be2, const float* m2, const float* v2,
    const float* w3, const float* b3, float* __restrict__ out) {
  const int b = blockIdx.x, tid = threadIdx.x;
  __shared__ float xb[128], y1[128], y2[64];
  xb[tid] = (pooled[b * 128 + tid] - m1[tid]) * rsqrtf(v1[tid] + 1e-5f) * g1[tid] + be1[tid];
  __syncthreads();
  float a = b1[tid];
#pragma unroll 8
  for (int k = 0; k < 128; ++k) a = fmaf(xb[k], w1[tid * 128 + k], a);
  y1[tid] = fmaxf(a, 0.f);
  __syncthreads();
  if (tid < 64) {
    float a2 = b2[tid];
#pragma unroll 8
    for (int k = 0; k < 128; ++k) a2 = fmaf(y1[k], w2[tid * 128 + k], a2);
    if (a2 < 0.f) a2 = exp2f(a2 * 1.4426950408889634f) - 1.0f;  // elu
    y2[tid] = (a2 - m2[tid]) * rsqrtf(v2[tid] + 1e-5f) * g2[tid] + be2[tid];
  }
  __syncthreads();
  if (tid < 3) {
    float a3 = b3[tid];
#pragma unroll
    for (int k = 0; k < 64; ++k) a3 = fmaf(y2[k], w3[tid * 64 + k], a3);
    out[b * 3 + tid] = a3;
  }
}

extern "C" void kernel_launch(void* const* d_in, const int* in_sizes, int n_in,
                              void* d_out, int out_size, void* d_ws, size_t ws_size,
                              hipStream_t stream) {
  const float* x      = (const float*)d_in[0];
  const float* w_proj = (const float*)d_in[1];
  const float* b_proj = (const float*)d_in[2];
  const float* w_ih_l0 = (const float*)d_in[3];
  const float* w_hh_l0 = (const float*)d_in[4];
  const float* b_l0    = (const float*)d_in[5];
  const float* w_ih_r  = (const float*)d_in[6];  // [3,2,256,128]
  const float* w_hh_r  = (const float*)d_in[7];  // [3,2,256,64]
  const float* b_r     = (const float*)d_in[8];  // [3,2,256]
  const float* w_attn  = (const float*)d_in[9];
  const float* g1  = (const float*)d_in[11];
  const float* be1 = (const float*)d_in[12];
  const float* m1  = (const float*)d_in[13];
  const float* v1  = (const float*)d_in[14];
  const float* w1  = (const float*)d_in[15];
  const float* b1  = (const float*)d_in[16];
  const float* w2  = (const float*)d_in[17];
  const float* b2  = (const float*)d_in[18];
  const float* g2  = (const float*)d_in[19];
  const float* be2 = (const float*)d_in[20];
  const float* m2  = (const float*)d_in[21];
  const float* v2  = (const float*)d_in[22];
  const float* w3  = (const float*)d_in[23];
  const float* b3  = (const float*)d_in[24];
  float* out = (float*)d_out;

  // ws layout: bufA [T,B,128] | bufB [T,B,128]  (in0 and pooled overlay dead regions)
  float* bufA = (float*)d_ws;
  float* bufB = bufA + (size_t)T_LEN * BATCH * 128;
  float* in0 = bufB;     // [T,B,64]; dead once layer1 starts writing bufB
  float* pooled = bufA;  // reused after layer3 no longer reads bufA

  proj_kernel<<<T_LEN * BATCH / 4, 256, 0, stream>>>(x, w_proj, b_proj, in0);
  lstm_kernel<64><<<256, 768, 0, stream>>>(in0, bufA, w_ih_l0, w_hh_l0, b_l0);
  lstm_kernel<128><<<256, 768, 0, stream>>>(bufA, bufB, w_ih_r, w_hh_r, b_r);
  lstm_kernel<128><<<256, 768, 0, stream>>>(bufB, bufA, w_ih_r + 65536, w_hh_r + 32768, b_r + 512);
  lstm_kernel<128><<<256, 768, 0, stream>>>(bufA, bufB, w_ih_r + 131072, w_hh_r + 65536, b_r + 1024);
  attn_kernel<<<BATCH, 256, 0, stream>>>(bufB, w_attn, pooled);
  head_kernel<<<BATCH, 128, 0, stream>>>(pooled, g1, be1, m1, v1, w1, b1, w2, b2,
                                         g2, be2, m2, v2, w3, b3, out);
}

// Round 6
// 8380.044 us; speedup vs baseline: 1.4525x; 1.0960x over previous
//
#include <hip/hip_runtime.h>
#include <cstdint>
#include <cstddef>

#define T_LEN 2048
#define BATCH 128

__device__ __forceinline__ float bcast(float v, int l) {
  return __uint_as_float(__builtin_amdgcn_readlane(__float_as_uint(v), (unsigned)l));
}
__device__ __forceinline__ float sigm(float x) {
  return __builtin_amdgcn_rcpf(1.0f + exp2f(-1.4426950408889634f * x));
}
__device__ __forceinline__ float tanh_fast(float x) {
  return 1.0f - 2.0f * __builtin_amdgcn_rcpf(1.0f + exp2f(2.8853900817779268f * x));
}

// lgkm-only fence + raw barrier: LDS writes visible across waves, but vmcnt
// (global prefetch loads, h-stores) stays in flight across the barrier.
#define BAR()                                              \
  do {                                                     \
    asm volatile("s_waitcnt lgkmcnt(0)" ::: "memory");     \
    __builtin_amdgcn_s_barrier();                          \
    asm volatile("" ::: "memory");                         \
  } while (0)

// ---------------- proj: in0[t*B+b, j] = relu(x[b,t,:] . w_proj[j,:] + b_proj[j])
__global__ __launch_bounds__(256) void proj_kernel(
    const float* __restrict__ x, const float* __restrict__ w_proj,
    const float* __restrict__ b_proj, float* __restrict__ in0) {
  int R = blockIdx.x * 4 + (threadIdx.x >> 6);  // R = t*BATCH + b
  int j = threadIdx.x & 63;
  int t = R >> 7;
  int b = R & 127;
  const float* xr = x + ((size_t)b * T_LEN + t) * 32;
  const float* wr = w_proj + j * 32;
  float a = b_proj[j];
#pragma unroll
  for (int k = 0; k < 32; ++k) a = fmaf(xr[k], wr[k], a);
  in0[(size_t)R * 64 + j] = fmaxf(a, 0.f);
}

// ---------------- persistent bidirectional LSTM layer, producer/consumer waves
// block = (batch b, direction dir); 768 threads = 12 waves (3/SIMD: 1 consumer
// + 2 producers).
// R6 = R5 minus s_setprio: race bisection. R5 diverged post-timing (1.5e-4);
// all LDS exchanges are >=1-barrier separated (audited), producer code is
// byte-identical to the R4 kernel that passed post-timing validation, so the
// only unverifiable new element was the persistent setprio(1) on consumer
// waves. This round removes ONLY that.
// Consumer wave cw = oh + 2*kh: rows {oh*128+l, oh*128+64+l}, K-half kh
//   -> 32 readlanes + 64 fma per wave; partials exchanged via zb[par][256][2].
// Gates are computed redundantly by all 4 consumer waves (h stays in-register).
// Producer wave pw = og + 2*ks as in R4 (readlane x-broadcast, K-slice ks).
template <int DIN>
__global__ __attribute__((amdgpu_flat_work_group_size(768, 768),
                          amdgpu_waves_per_eu(3)))
void lstm_kernel(
    const float* __restrict__ in,    // [T, B, DIN]
    float* __restrict__ out,         // [T, B, 128] (dir0 -> [0:64), dir1 -> [64:128))
    const float* __restrict__ w_ih,  // [2, 256, DIN]
    const float* __restrict__ w_hh,  // [2, 256, 64]
    const float* __restrict__ bias)  // [2, 256]
{
  constexpr int KW = DIN / 4;           // K per producer wave (32 / 16)
  constexpr int NF4W = KW / 4;          // float4 per producer row-slice (8 / 4)
  constexpr int SREG = 16 * DIN / 512;  // refill elems per producer thread (4/2)
  constexpr int IREG = 32 * DIN / 512;  // initial-fill elems per producer (8/4)
  const int LEAD = 4;

  const int tid = threadIdx.x;
  const int dir = blockIdx.x & 1;
  const int b = blockIdx.x >> 1;
  const bool is_prod = tid >= 256;
  const int ptid = tid - 256;  // producer index 0..511
  const int pw = ptid >> 6;    // producer wave 0..7
  const int og = pw & 1;       // producer output half
  const int ks = pw >> 1;      // producer K-slice
  const int l = tid & 63;      // lane
  const int cw = tid >> 6;     // consumer wave 0..3
  const int oh = cw & 1;       // consumer output half
  const int kh = cw >> 1;      // consumer K-half
  const int r0 = oh * 128 + l;
  const int r1 = oh * 128 + 64 + l;

  __shared__ float xring[32][DIN];    // input rows (traversal order), ring
  __shared__ float preh[8][4][256];   // partial pre-activations [slot][ks][g]
  __shared__ float zb[2][256][2];     // z partials [parity][g][kh]

  // ---- ONE register array, loaded per-branch (shared storage!)
  float4 w[16];
  float bz0 = 0.f, bz1 = 0.f;
  if (is_prod) {
    // rows og*128+l and og*128+64+l, cols [KW*ks, KW*ks+KW)
    const float4* q0 = (const float4*)(w_ih + (size_t)(dir * 256 + og * 128 + l) * DIN + KW * ks);
    const float4* q1 = (const float4*)(w_ih + (size_t)(dir * 256 + og * 128 + 64 + l) * DIN + KW * ks);
#pragma unroll
    for (int k = 0; k < NF4W; ++k) w[k] = q0[k];
#pragma unroll
    for (int k = 0; k < NF4W; ++k) w[NF4W + k] = q1[k];
  } else {
    // rows r0, r1, K-half kh (32 floats each)
    const float4* q0 = (const float4*)(w_hh + (size_t)(dir * 256 + r0) * 64 + kh * 32);
    const float4* q1 = (const float4*)(w_hh + (size_t)(dir * 256 + r1) * 64 + kh * 32);
#pragma unroll
    for (int k = 0; k < 8; ++k) w[k] = q0[k];
#pragma unroll
    for (int k = 0; k < 8; ++k) w[8 + k] = q1[k];
    if (kh == 0) {
      bz0 = bias[dir * 256 + r0];
      bz1 = bias[dir * 256 + r1];
    }
  }

  // ---- initial x-ring fill: rows 0..31 in traversal order (producers only)
  if (is_prod) {
#pragma unroll
    for (int q = 0; q < IREG; ++q) {
      int idx = ptid + 512 * q;
      int r = idx / DIN;
      int col = idx % DIN;
      int t = dir ? (T_LEN - 1 - r) : r;
      xring[r][col] = in[((size_t)t * BATCH + b) * DIN + col];
    }
  }
  __syncthreads();

  float c = 0.f, h = 0.f;
  float stg[SREG];
  // wave-uniform readlane base for the producer x slice
  const int rlbase = __builtin_amdgcn_readfirstlane((ks * KW) & 63);
  const bool xhigh = (ks * KW) >= 64;

  for (int i = 0; i < T_LEN + LEAD; ++i) {
    if (is_prod) {
      if (i < T_LEN) {
        // refill ISSUE: rows i+16..i+31 into regs (LDS-written 8 iters later)
        if ((i & 15) == 0 && i > 0 && i + 16 < T_LEN) {
#pragma unroll
          for (int q = 0; q < SREG; ++q) {
            int idx = ptid + 512 * q;
            int r = i + 16 + idx / DIN;
            int col = idx % DIN;
            int t = dir ? (T_LEN - 1 - r) : r;
            stg[q] = in[((size_t)t * BATCH + b) * DIN + col];
          }
        }
        // stage x row lane-sliced (per-lane distinct reads, ~512 B/wave)
        const int slot = i & 31;
        float xv0 = xring[slot][l];
        float xs;
        if constexpr (DIN == 128) {
          float xv1 = xring[slot][64 + l];
          xs = xhigh ? xv1 : xv0;
        } else {
          xs = xv0;
        }
        // partial dots: outputs og*128+l, og*128+64+l over K-slice ks
        const float* wf = (const float*)w;
        float a0 = 0.f, a1 = 0.f;
#pragma unroll
        for (int k = 0; k < KW; ++k) {
          float sx = bcast(xs, rlbase + k);
          a0 = fmaf(sx, wf[k], a0);
          a1 = fmaf(sx, wf[KW + k], a1);
        }
        preh[i & 7][ks][og * 128 + l] = a0;
        preh[i & 7][ks][og * 128 + 64 + l] = a1;
        // refill WRITE: loads issued at i-8 have arrived (~8 steps of slack)
        if ((i & 15) == 8 && i > 8 && (i - 8) + 16 < T_LEN) {
#pragma unroll
          for (int q = 0; q < SREG; ++q) {
            int idx = ptid + 512 * q;
            int r = (i - 8) + 16 + idx / DIN;
            int col = idx % DIN;
            xring[r & 31][col] = stg[q];
          }
        }
      }
    } else {
      int s = i - LEAD;
      if (s >= 0) {
        // issue pre-partial reads early (independent of h -> latency hidden)
        float pr0 = preh[s & 7][2 * kh + 0][r0];
        float pr1 = preh[s & 7][2 * kh + 1][r0];
        float pr2 = preh[s & 7][2 * kh + 0][r1];
        float pr3 = preh[s & 7][2 * kh + 1][r1];
        if (s > 0) {
          // gather z partials of step s-1 (4 x ds_read_b64), gates -> c,h
          const float2* zp = (const float2*)&zb[(s - 1) & 1][0][0];
          float2 vi = zp[l];
          float2 vf = zp[64 + l];
          float2 vg = zp[128 + l];
          float2 vo = zp[192 + l];
          float zi = vi.x + vi.y, zf = vf.x + vf.y;
          float zg = vg.x + vg.y, zo = vo.x + vo.y;
          float ig = sigm(zi), fg = sigm(zf), gg = tanh_fast(zg), og_ = sigm(zo);
          c = fmaf(fg, c, ig * gg);
          h = og_ * tanh_fast(c);
          if (tid < 64) {  // cw==0 stores h (vmcnt never drained in-loop)
            int tp = dir ? (T_LEN - s) : (s - 1);
            out[((size_t)tp * BATCH + b) * 128 + dir * 64 + l] = h;
          }
        }
        // partial recurrent dot over K-half kh (32 RL + 64 FMA)
        float p0 = (bz0 + pr0) + pr1;
        float p1 = (bz1 + pr2) + pr3;
        const float* wf = (const float*)w;
        if (kh == 0) {
#pragma unroll
          for (int k = 0; k < 32; ++k) {
            float sx = bcast(h, k);
            p0 = fmaf(sx, wf[k], p0);
            p1 = fmaf(sx, wf[32 + k], p1);
          }
        } else {
#pragma unroll
          for (int k = 0; k < 32; ++k) {
            float sx = bcast(h, 32 + k);
            p0 = fmaf(sx, wf[k], p0);
            p1 = fmaf(sx, wf[32 + k], p1);
          }
        }
        zb[s & 1][r0][kh] = p0;
        zb[s & 1][r1][kh] = p1;
      }
    }
    BAR();
  }

  // epilogue: gates of final step s=T-1 (consumer wave 0 only)
  if (tid < 64) {
    const int pb = (T_LEN - 1) & 1;
    const float2* zp = (const float2*)&zb[pb][0][0];
    float2 vi = zp[l];
    float2 vf = zp[64 + l];
    float2 vg = zp[128 + l];
    float2 vo = zp[192 + l];
    float zi = vi.x + vi.y, zf = vf.x + vf.y;
    float zg = vg.x + vg.y, zo = vo.x + vo.y;
    float ig = sigm(zi), fg = sigm(zf), gg = tanh_fast(zg), og_ = sigm(zo);
    c = fmaf(fg, c, ig * gg);
    h = og_ * tanh_fast(c);
    int tp = dir ? 0 : (T_LEN - 1);
    out[((size_t)tp * BATCH + b) * 128 + dir * 64 + l] = h;
  }
}

// ---------------- attention: scores + softmax + pooled, one block per batch row
__global__ __launch_bounds__(256) void attn_kernel(
    const float* __restrict__ hs,      // [T, B, 128]
    const float* __restrict__ w_attn,  // [128]
    float* __restrict__ pooled)        // [B, 128]
{
  const int b = blockIdx.x, tid = threadIdx.x;
  __shared__ float wa[128];
  __shared__ float sc[T_LEN];
  __shared__ float red[256];
  if (tid < 128) wa[tid] = w_attn[tid];
  __syncthreads();

  float lmax = -3.4e38f;
#pragma unroll
  for (int i = 0; i < T_LEN / 256; ++i) {
    int t = tid + 256 * i;
    const float4* r4 = (const float4*)(hs + ((size_t)t * BATCH + b) * 128);
    float s = 0.f;
#pragma unroll
    for (int k = 0; k < 32; ++k) {
      float4 v = r4[k];
      s += v.x * wa[4 * k] + v.y * wa[4 * k + 1] + v.z * wa[4 * k + 2] + v.w * wa[4 * k + 3];
    }
    sc[t] = s;
    lmax = fmaxf(lmax, s);
  }
  red[tid] = lmax;
  __syncthreads();
  for (int off = 128; off > 0; off >>= 1) {
    if (tid < off) red[tid] = fmaxf(red[tid], red[tid + off]);
    __syncthreads();
  }
  float m = red[0];
  __syncthreads();

  float lsum = 0.f;
#pragma unroll
  for (int i = 0; i < T_LEN / 256; ++i) {
    int t = tid + 256 * i;
    float e = exp2f((sc[t] - m) * 1.4426950408889634f);
    sc[t] = e;
    lsum += e;
  }
  red[tid] = lsum;
  __syncthreads();
  for (int off = 128; off > 0; off >>= 1) {
    if (tid < off) red[tid] += red[tid + off];
    __syncthreads();
  }
  float inv = __builtin_amdgcn_rcpf(red[0]);

  if (tid < 128) {
    float a0 = 0.f, a1 = 0.f, a2 = 0.f, a3 = 0.f;
    for (int t = 0; t < T_LEN; t += 4) {
      a0 = fmaf(sc[t], hs[((size_t)t * BATCH + b) * 128 + tid], a0);
      a1 = fmaf(sc[t + 1], hs[((size_t)(t + 1) * BATCH + b) * 128 + tid], a1);
      a2 = fmaf(sc[t + 2], hs[((size_t)(t + 2) * BATCH + b) * 128 + tid], a2);
      a3 = fmaf(sc[t + 3], hs[((size_t)(t + 3) * BATCH + b) * 128 + tid], a3);
    }
    pooled[b * 128 + tid] = ((a0 + a1) + (a2 + a3)) * inv;
  }
}

// ---------------- head: BN1 -> fc1 -> relu -> fc2 -> elu -> BN2 -> fc3
__global__ __launch_bounds__(128) void head_kernel(
    const float* __restrict__ pooled,
    const float* g1, const float* be1, const float* m1, const float* v1,
    const float* w1, const float* b1, const float* w2, const float* b2,
    const float* g2, const float* be2, const float* m2, const float* v2,
    const float* w3, const float* b3, float* __restrict__ out) {
  const int b = blockIdx.x, tid = threadIdx.x;
  __shared__ float xb[128], y1[128], y2[64];
  xb[tid] = (pooled[b * 128 + tid] - m1[tid]) * rsqrtf(v1[tid] + 1e-5f) * g1[tid] + be1[tid];
  __syncthreads();
  float a = b1[tid];
#pragma unroll 8
  for (int k = 0; k < 128; ++k) a = fmaf(xb[k], w1[tid * 128 + k], a);
  y1[tid] = fmaxf(a, 0.f);
  __syncthreads();
  if (tid < 64) {
    float a2 = b2[tid];
#pragma unroll 8
    for (int k = 0; k < 128; ++k) a2 = fmaf(y1[k], w2[tid * 128 + k], a2);
    if (a2 < 0.f) a2 = exp2f(a2 * 1.4426950408889634f) - 1.0f;  // elu
    y2[tid] = (a2 - m2[tid]) * rsqrtf(v2[tid] + 1e-5f) * g2[tid] + be2[tid];
  }
  __syncthreads();
  if (tid < 3) {
    float a3 = b3[tid];
#pragma unroll
    for (int k = 0; k < 64; ++k) a3 = fmaf(y2[k], w3[tid * 64 + k], a3);
    out[b * 3 + tid] = a3;
  }
}

extern "C" void kernel_launch(void* const* d_in, const int* in_sizes, int n_in,
                              void* d_out, int out_size, void* d_ws, size_t ws_size,
                              hipStream_t stream) {
  const float* x      = (const float*)d_in[0];
  const float* w_proj = (const float*)d_in[1];
  const float* b_proj = (const float*)d_in[2];
  const float* w_ih_l0 = (const float*)d_in[3];
  const float* w_hh_l0 = (const float*)d_in[4];
  const float* b_l0    = (const float*)d_in[5];
  const float* w_ih_r  = (const float*)d_in[6];  // [3,2,256,128]
  const float* w_hh_r  = (const float*)d_in[7];  // [3,2,256,64]
  const float* b_r     = (const float*)d_in[8];  // [3,2,256]
  const float* w_attn  = (const float*)d_in[9];
  const float* g1  = (const float*)d_in[11];
  const float* be1 = (const float*)d_in[12];
  const float* m1  = (const float*)d_in[13];
  const float* v1  = (const float*)d_in[14];
  const float* w1  = (const float*)d_in[15];
  const float* b1  = (const float*)d_in[16];
  const float* w2  = (const float*)d_in[17];
  const float* b2  = (const float*)d_in[18];
  const float* g2  = (const float*)d_in[19];
  const float* be2 = (const float*)d_in[20];
  const float* m2  = (const float*)d_in[21];
  const float* v2  = (const float*)d_in[22];
  const float* w3  = (const float*)d_in[23];
  const float* b3  = (const float*)d_in[24];
  float* out = (float*)d_out;

  // ws layout: bufA [T,B,128] | bufB [T,B,128]  (in0 and pooled overlay dead regions)
  float* bufA = (float*)d_ws;
  float* bufB = bufA + (size_t)T_LEN * BATCH * 128;
  float* in0 = bufB;     // [T,B,64]; dead once layer1 starts writing bufB
  float* pooled = bufA;  // reused after layer3 no longer reads bufA

  proj_kernel<<<T_LEN * BATCH / 4, 256, 0, stream>>>(x, w_proj, b_proj, in0);
  lstm_kernel<64><<<256, 768, 0, stream>>>(in0, bufA, w_ih_l0, w_hh_l0, b_l0);
  lstm_kernel<128><<<256, 768, 0, stream>>>(bufA, bufB, w_ih_r, w_hh_r, b_r);
  lstm_kernel<128><<<256, 768, 0, stream>>>(bufB, bufA, w_ih_r + 65536, w_hh_r + 32768, b_r + 512);
  lstm_kernel<128><<<256, 768, 0, stream>>>(bufA, bufB, w_ih_r + 131072, w_hh_r + 65536, b_r + 1024);
  attn_kernel<<<BATCH, 256, 0, stream>>>(bufB, w_attn, pooled);
  head_kernel<<<BATCH, 128, 0, stream>>>(pooled, g1, be1, m1, v1, w1, b1, w2, b2,
                                         g2, be2, m2, v2, w3, b3, out);
}

// Round 7
// 8344.492 us; speedup vs baseline: 1.4587x; 1.0043x over previous
//
#include <hip/hip_runtime.h>
#include <cstdint>
#include <cstddef>

#define T_LEN 2048
#define BATCH 128

__device__ __forceinline__ float bcast(float v, int l) {
  return __uint_as_float(__builtin_amdgcn_readlane(__float_as_uint(v), (unsigned)l));
}
__device__ __forceinline__ float sigm(float x) {
  return __builtin_amdgcn_rcpf(1.0f + exp2f(-1.4426950408889634f * x));
}
__device__ __forceinline__ float tanh_fast(float x) {
  return 1.0f - 2.0f * __builtin_amdgcn_rcpf(1.0f + exp2f(2.8853900817779268f * x));
}

#define BAR()                                              \
  do {                                                     \
    asm volatile("s_waitcnt lgkmcnt(0)" ::: "memory");     \
    __builtin_amdgcn_s_barrier();                          \
    asm volatile("" ::: "memory");                         \
  } while (0)

// ---------------- proj: in0[t*B+b, j] = relu(x[b,t,:] . w_proj[j,:] + b_proj[j])
__global__ __launch_bounds__(256) void proj_kernel(
    const float* __restrict__ x, const float* __restrict__ w_proj,
    const float* __restrict__ b_proj, float* __restrict__ in0) {
  int R = blockIdx.x * 4 + (threadIdx.x >> 6);  // R = t*BATCH + b
  int j = threadIdx.x & 63;
  int t = R >> 7;
  int b = R & 127;
  const float* xr = x + ((size_t)b * T_LEN + t) * 32;
  const float* wr = w_proj + j * 32;
  float a = b_proj[j];
#pragma unroll
  for (int k = 0; k < 32; ++k) a = fmaf(xr[k], wr[k], a);
  in0[(size_t)R * 64 + j] = fmaxf(a, 0.f);
}

// ================= NEW PATH =================
// pre_gemm: P[r][g'] = bias[g'] + A[r][:].W[g'][:]   (M=T*B rows, 512 cols)
// block: 256 thr, tile 64 rows x 64 cols. A^T and W staged in LDS, pads chosen
// conflict-free ((4k+r)%32 and (c+k)%32 both spread across consecutive lanes).
template <int K>
__global__ __launch_bounds__(256, 2) void pre_gemm(
    const float* __restrict__ A,     // [M][K]
    const float* __restrict__ W,     // [512][K]
    const float* __restrict__ bias,  // [512]
    float* __restrict__ P)           // [M][512]
{
  __shared__ float At[K][68];      // [k][r], 16B-aligned rows, free writes
  __shared__ float Wl[64][K + 1];  // [c][k], free scalar reads/writes
  const int tid = threadIdx.x;
  const size_t r0 = (size_t)blockIdx.x * 64;
  const int c0 = blockIdx.y * 64;

  {
    const int rc = tid & 63;     // row (for A) / col (for W) handled by this thread
    const int kg0 = tid >> 6;    // k-group 0..3
#pragma unroll
    for (int q = 0; q < K / 16; ++q) {
      int k = 4 * (kg0 + 4 * q);
      float4 va = *(const float4*)(A + (r0 + rc) * K + k);
      At[k][rc] = va.x; At[k + 1][rc] = va.y; At[k + 2][rc] = va.z; At[k + 3][rc] = va.w;
      float4 vw = *(const float4*)(W + (size_t)(c0 + rc) * K + k);
      Wl[rc][k] = vw.x; Wl[rc][k + 1] = vw.y; Wl[rc][k + 2] = vw.z; Wl[rc][k + 3] = vw.w;
    }
  }
  __syncthreads();

  const int w = tid >> 6;   // wave -> rows w*16..w*16+15
  const int cc = tid & 63;  // col within tile
  float acc[16];
#pragma unroll
  for (int i = 0; i < 16; ++i) acc[i] = 0.f;

#pragma unroll 4
  for (int k = 0; k < K; k += 4) {
    float w0 = Wl[cc][k], w1 = Wl[cc][k + 1], w2 = Wl[cc][k + 2], w3 = Wl[cc][k + 3];
#pragma unroll
    for (int i = 0; i < 4; ++i) {
      float4 a0 = *(const float4*)&At[k][w * 16 + 4 * i];
      float4 a1 = *(const float4*)&At[k + 1][w * 16 + 4 * i];
      float4 a2 = *(const float4*)&At[k + 2][w * 16 + 4 * i];
      float4 a3 = *(const float4*)&At[k + 3][w * 16 + 4 * i];
      acc[4 * i + 0] = fmaf(a0.x, w0, acc[4 * i + 0]);
      acc[4 * i + 1] = fmaf(a0.y, w0, acc[4 * i + 1]);
      acc[4 * i + 2] = fmaf(a0.z, w0, acc[4 * i + 2]);
      acc[4 * i + 3] = fmaf(a0.w, w0, acc[4 * i + 3]);
      acc[4 * i + 0] = fmaf(a1.x, w1, acc[4 * i + 0]);
      acc[4 * i + 1] = fmaf(a1.y, w1, acc[4 * i + 1]);
      acc[4 * i + 2] = fmaf(a1.z, w1, acc[4 * i + 2]);
      acc[4 * i + 3] = fmaf(a1.w, w1, acc[4 * i + 3]);
      acc[4 * i + 0] = fmaf(a2.x, w2, acc[4 * i + 0]);
      acc[4 * i + 1] = fmaf(a2.y, w2, acc[4 * i + 1]);
      acc[4 * i + 2] = fmaf(a2.z, w2, acc[4 * i + 2]);
      acc[4 * i + 3] = fmaf(a2.w, w2, acc[4 * i + 3]);
      acc[4 * i + 0] = fmaf(a3.x, w3, acc[4 * i + 0]);
      acc[4 * i + 1] = fmaf(a3.y, w3, acc[4 * i + 1]);
      acc[4 * i + 2] = fmaf(a3.z, w3, acc[4 * i + 2]);
      acc[4 * i + 3] = fmaf(a3.w, w3, acc[4 * i + 3]);
    }
  }
  float bv = bias[c0 + cc];
#pragma unroll
  for (int i = 0; i < 16; ++i)
    P[(r0 + w * 16 + i) * 512 + c0 + cc] = acc[i] + bv;
}

// lstm_seq: one wave per (b,dir) chain. Zero barriers, zero cross-wave traffic.
// Lane j owns hidden unit j: gate rows {j,64+j,128+j,192+j} of w_hh in 256 VGPR,
// gates fully in-lane; h broadcast via in-wave LDS write + uniform b128 reads
// (same-wave DS ops are program-ordered -> no sync). pre streamed via 4-deep
// statically-indexed register ring (loop unrolled x4 so slot==position).
__global__ __launch_bounds__(64, 1) void lstm_seq(
    const float* __restrict__ pre,   // [T*B][512], bias folded in
    const float* __restrict__ w_hh,  // [2][256][64]
    float* __restrict__ out)         // [T*B][128]
{
  const int dir = blockIdx.x & 1;
  const int b = blockIdx.x >> 1;
  const int j = threadIdx.x;
  __shared__ float hb[64];

  float4 wi[16], wf[16], wg[16], wo[16];
  {
    const float4* qi = (const float4*)(w_hh + (size_t)(dir * 256 + 0 + j) * 64);
    const float4* qf = (const float4*)(w_hh + (size_t)(dir * 256 + 64 + j) * 64);
    const float4* qg = (const float4*)(w_hh + (size_t)(dir * 256 + 128 + j) * 64);
    const float4* qo = (const float4*)(w_hh + (size_t)(dir * 256 + 192 + j) * 64);
#pragma unroll
    for (int k = 0; k < 16; ++k) {
      wi[k] = qi[k]; wf[k] = qf[k]; wg[k] = qg[k]; wo[k] = qo[k];
    }
  }
  hb[j] = 0.f;
  float h = 0.f, c = 0.f;
  const int base = dir * 256 + j;

#define ROF(t) ((size_t)(dir ? (T_LEN - 1 - (t)) : (t)) * BATCH + b)

  float ring[4][4];
#pragma unroll
  for (int p = 0; p < 4; ++p) {
    const float* pp = pre + ROF(p) * 512 + base;
    ring[p][0] = pp[0]; ring[p][1] = pp[64]; ring[p][2] = pp[128]; ring[p][3] = pp[192];
  }

  for (int t4 = 0; t4 < T_LEN / 4; ++t4) {
#pragma unroll
    for (int p = 0; p < 4; ++p) {
      const int t = t4 * 4 + p;
      float zi = ring[p][0], zf = ring[p][1], zg = ring[p][2], zo = ring[p][3];
      // refill slot p for step t+4 (issued early; vmcnt waited 4 steps later)
      if (t + 4 < T_LEN) {
        const float* pp = pre + ROF(t + 4) * 512 + base;
        ring[p][0] = pp[0]; ring[p][1] = pp[64]; ring[p][2] = pp[128]; ring[p][3] = pp[192];
      }
      // z += W_hh . h_{t-1}  (h broadcast: 16 uniform b128 reads, 256 FMA)
#pragma unroll
      for (int k = 0; k < 16; ++k) {
        float4 h4 = *(const float4*)&hb[4 * k];
        zi = fmaf(h4.x, wi[k].x, zi); zf = fmaf(h4.x, wf[k].x, zf);
        zg = fmaf(h4.x, wg[k].x, zg); zo = fmaf(h4.x, wo[k].x, zo);
        zi = fmaf(h4.y, wi[k].y, zi); zf = fmaf(h4.y, wf[k].y, zf);
        zg = fmaf(h4.y, wg[k].y, zg); zo = fmaf(h4.y, wo[k].y, zo);
        zi = fmaf(h4.z, wi[k].z, zi); zf = fmaf(h4.z, wf[k].z, zf);
        zg = fmaf(h4.z, wg[k].z, zg); zo = fmaf(h4.z, wo[k].z, zo);
        zi = fmaf(h4.w, wi[k].w, zi); zf = fmaf(h4.w, wf[k].w, zf);
        zg = fmaf(h4.w, wg[k].w, zg); zo = fmaf(h4.w, wo[k].w, zo);
      }
      float ig = sigm(zi), fg = sigm(zf), gg = tanh_fast(zg), og = sigm(zo);
      c = fmaf(fg, c, ig * gg);
      h = og * tanh_fast(c);
      hb[j] = h;  // next iteration's reads are program-ordered after this
      out[ROF(t) * 128 + dir * 64 + j] = h;
    }
  }
#undef ROF
}

// ================= OLD PATH (R6, fallback if ws too small) =================
template <int DIN>
__global__ __attribute__((amdgpu_flat_work_group_size(768, 768),
                          amdgpu_waves_per_eu(3)))
void lstm_kernel(
    const float* __restrict__ in, float* __restrict__ out,
    const float* __restrict__ w_ih, const float* __restrict__ w_hh,
    const float* __restrict__ bias) {
  constexpr int KW = DIN / 4;
  constexpr int NF4W = KW / 4;
  constexpr int SREG = 16 * DIN / 512;
  constexpr int IREG = 32 * DIN / 512;
  const int LEAD = 4;
  const int tid = threadIdx.x;
  const int dir = blockIdx.x & 1;
  const int b = blockIdx.x >> 1;
  const bool is_prod = tid >= 256;
  const int ptid = tid - 256;
  const int pw = ptid >> 6;
  const int og = pw & 1;
  const int ks = pw >> 1;
  const int l = tid & 63;
  const int cw = tid >> 6;
  const int oh = cw & 1;
  const int kh = cw >> 1;
  const int r0 = oh * 128 + l;
  const int r1 = oh * 128 + 64 + l;

  __shared__ float xring[32][DIN];
  __shared__ float preh[8][4][256];
  __shared__ float zb[2][256][2];

  float4 w[16];
  float bz0 = 0.f, bz1 = 0.f;
  if (is_prod) {
    const float4* q0 = (const float4*)(w_ih + (size_t)(dir * 256 + og * 128 + l) * DIN + KW * ks);
    const float4* q1 = (const float4*)(w_ih + (size_t)(dir * 256 + og * 128 + 64 + l) * DIN + KW * ks);
#pragma unroll
    for (int k = 0; k < NF4W; ++k) w[k] = q0[k];
#pragma unroll
    for (int k = 0; k < NF4W; ++k) w[NF4W + k] = q1[k];
  } else {
    const float4* q0 = (const float4*)(w_hh + (size_t)(dir * 256 + r0) * 64 + kh * 32);
    const float4* q1 = (const float4*)(w_hh + (size_t)(dir * 256 + r1) * 64 + kh * 32);
#pragma unroll
    for (int k = 0; k < 8; ++k) w[k] = q0[k];
#pragma unroll
    for (int k = 0; k < 8; ++k) w[8 + k] = q1[k];
    if (kh == 0) {
      bz0 = bias[dir * 256 + r0];
      bz1 = bias[dir * 256 + r1];
    }
  }
  if (is_prod) {
#pragma unroll
    for (int q = 0; q < IREG; ++q) {
      int idx = ptid + 512 * q;
      int r = idx / DIN;
      int col = idx % DIN;
      int t = dir ? (T_LEN - 1 - r) : r;
      xring[r][col] = in[((size_t)t * BATCH + b) * DIN + col];
    }
  }
  __syncthreads();

  float c = 0.f, h = 0.f;
  float stg[SREG];
  const int rlbase = __builtin_amdgcn_readfirstlane((ks * KW) & 63);
  const bool xhigh = (ks * KW) >= 64;

  for (int i = 0; i < T_LEN + LEAD; ++i) {
    if (is_prod) {
      if (i < T_LEN) {
        if ((i & 15) == 0 && i > 0 && i + 16 < T_LEN) {
#pragma unroll
          for (int q = 0; q < SREG; ++q) {
            int idx = ptid + 512 * q;
            int r = i + 16 + idx / DIN;
            int col = idx % DIN;
            int t = dir ? (T_LEN - 1 - r) : r;
            stg[q] = in[((size_t)t * BATCH + b) * DIN + col];
          }
        }
        const int slot = i & 31;
        float xv0 = xring[slot][l];
        float xs;
        if constexpr (DIN == 128) {
          float xv1 = xring[slot][64 + l];
          xs = xhigh ? xv1 : xv0;
        } else {
          xs = xv0;
        }
        const float* wf = (const float*)w;
        float a0 = 0.f, a1 = 0.f;
#pragma unroll
        for (int k = 0; k < KW; ++k) {
          float sx = bcast(xs, rlbase + k);
          a0 = fmaf(sx, wf[k], a0);
          a1 = fmaf(sx, wf[KW + k], a1);
        }
        preh[i & 7][ks][og * 128 + l] = a0;
        preh[i & 7][ks][og * 128 + 64 + l] = a1;
        if ((i & 15) == 8 && i > 8 && (i - 8) + 16 < T_LEN) {
#pragma unroll
          for (int q = 0; q < SREG; ++q) {
            int idx = ptid + 512 * q;
            int r = (i - 8) + 16 + idx / DIN;
            int col = idx % DIN;
            xring[r & 31][col] = stg[q];
          }
        }
      }
    } else {
      int s = i - LEAD;
      if (s >= 0) {
        float pr0 = preh[s & 7][2 * kh + 0][r0];
        float pr1 = preh[s & 7][2 * kh + 1][r0];
        float pr2 = preh[s & 7][2 * kh + 0][r1];
        float pr3 = preh[s & 7][2 * kh + 1][r1];
        if (s > 0) {
          const float2* zp = (const float2*)&zb[(s - 1) & 1][0][0];
          float2 vi = zp[l];
          float2 vf = zp[64 + l];
          float2 vg = zp[128 + l];
          float2 vo = zp[192 + l];
          float zi = vi.x + vi.y, zf = vf.x + vf.y;
          float zg = vg.x + vg.y, zo = vo.x + vo.y;
          float ig = sigm(zi), fg = sigm(zf), gg = tanh_fast(zg), og_ = sigm(zo);
          c = fmaf(fg, c, ig * gg);
          h = og_ * tanh_fast(c);
          if (tid < 64) {
            int tp = dir ? (T_LEN - s) : (s - 1);
            out[((size_t)tp * BATCH + b) * 128 + dir * 64 + l] = h;
          }
        }
        float p0 = (bz0 + pr0) + pr1;
        float p1 = (bz1 + pr2) + pr3;
        const float* wf = (const float*)w;
        if (kh == 0) {
#pragma unroll
          for (int k = 0; k < 32; ++k) {
            float sx = bcast(h, k);
            p0 = fmaf(sx, wf[k], p0);
            p1 = fmaf(sx, wf[32 + k], p1);
          }
        } else {
#pragma unroll
          for (int k = 0; k < 32; ++k) {
            float sx = bcast(h, 32 + k);
            p0 = fmaf(sx, wf[k], p0);
            p1 = fmaf(sx, wf[32 + k], p1);
          }
        }
        zb[s & 1][r0][kh] = p0;
        zb[s & 1][r1][kh] = p1;
      }
    }
    BAR();
  }
  if (tid < 64) {
    const int pb = (T_LEN - 1) & 1;
    const float2* zp = (const float2*)&zb[pb][0][0];
    float2 vi = zp[l];
    float2 vf = zp[64 + l];
    float2 vg = zp[128 + l];
    float2 vo = zp[192 + l];
    float zi = vi.x + vi.y, zf = vf.x + vf.y;
    float zg = vg.x + vg.y, zo = vo.x + vo.y;
    float ig = sigm(zi), fg = sigm(zf), gg = tanh_fast(zg), og_ = sigm(zo);
    c = fmaf(fg, c, ig * gg);
    h = og_ * tanh_fast(c);
    int tp = dir ? 0 : (T_LEN - 1);
    out[((size_t)tp * BATCH + b) * 128 + dir * 64 + l] = h;
  }
}

// ---------------- attention
__global__ __launch_bounds__(256) void attn_kernel(
    const float* __restrict__ hs, const float* __restrict__ w_attn,
    float* __restrict__ pooled) {
  const int b = blockIdx.x, tid = threadIdx.x;
  __shared__ float wa[128];
  __shared__ float sc[T_LEN];
  __shared__ float red[256];
  if (tid < 128) wa[tid] = w_attn[tid];
  __syncthreads();

  float lmax = -3.4e38f;
#pragma unroll
  for (int i = 0; i < T_LEN / 256; ++i) {
    int t = tid + 256 * i;
    const float4* r4 = (const float4*)(hs + ((size_t)t * BATCH + b) * 128);
    float s = 0.f;
#pragma unroll
    for (int k = 0; k < 32; ++k) {
      float4 v = r4[k];
      s += v.x * wa[4 * k] + v.y * wa[4 * k + 1] + v.z * wa[4 * k + 2] + v.w * wa[4 * k + 3];
    }
    sc[t] = s;
    lmax = fmaxf(lmax, s);
  }
  red[tid] = lmax;
  __syncthreads();
  for (int off = 128; off > 0; off >>= 1) {
    if (tid < off) red[tid] = fmaxf(red[tid], red[tid + off]);
    __syncthreads();
  }
  float m = red[0];
  __syncthreads();

  float lsum = 0.f;
#pragma unroll
  for (int i = 0; i < T_LEN / 256; ++i) {
    int t = tid + 256 * i;
    float e = exp2f((sc[t] - m) * 1.4426950408889634f);
    sc[t] = e;
    lsum += e;
  }
  red[tid] = lsum;
  __syncthreads();
  for (int off = 128; off > 0; off >>= 1) {
    if (tid < off) red[tid] += red[tid + off];
    __syncthreads();
  }
  float inv = __builtin_amdgcn_rcpf(red[0]);

  if (tid < 128) {
    float a0 = 0.f, a1 = 0.f, a2 = 0.f, a3 = 0.f;
    for (int t = 0; t < T_LEN; t += 4) {
      a0 = fmaf(sc[t], hs[((size_t)t * BATCH + b) * 128 + tid], a0);
      a1 = fmaf(sc[t + 1], hs[((size_t)(t + 1) * BATCH + b) * 128 + tid], a1);
      a2 = fmaf(sc[t + 2], hs[((size_t)(t + 2) * BATCH + b) * 128 + tid], a2);
      a3 = fmaf(sc[t + 3], hs[((size_t)(t + 3) * BATCH + b) * 128 + tid], a3);
    }
    pooled[b * 128 + tid] = ((a0 + a1) + (a2 + a3)) * inv;
  }
}

// ---------------- head
__global__ __launch_bounds__(128) void head_kernel(
    const float* __restrict__ pooled,
    const float* g1, const float* be1, const float* m1, const float* v1,
    const float* w1, const float* b1, const float* w2, const float* b2,
    const float* g2, const float* be2, const float* m2, const float* v2,
    const float* w3, const float* b3, float* __restrict__ out) {
  const int b = blockIdx.x, tid = threadIdx.x;
  __shared__ float xb[128], y1[128], y2[64];
  xb[tid] = (pooled[b * 128 + tid] - m1[tid]) * rsqrtf(v1[tid] + 1e-5f) * g1[tid] + be1[tid];
  __syncthreads();
  float a = b1[tid];
#pragma unroll 8
  for (int k = 0; k < 128; ++k) a = fmaf(xb[k], w1[tid * 128 + k], a);
  y1[tid] = fmaxf(a, 0.f);
  __syncthreads();
  if (tid < 64) {
    float a2 = b2[tid];
#pragma unroll 8
    for (int k = 0; k < 128; ++k) a2 = fmaf(y1[k], w2[tid * 128 + k], a2);
    if (a2 < 0.f) a2 = exp2f(a2 * 1.4426950408889634f) - 1.0f;  // elu
    y2[tid] = (a2 - m2[tid]) * rsqrtf(v2[tid] + 1e-5f) * g2[tid] + be2[tid];
  }
  __syncthreads();
  if (tid < 3) {
    float a3 = b3[tid];
#pragma unroll
    for (int k = 0; k < 64; ++k) a3 = fmaf(y2[k], w3[tid * 64 + k], a3);
    out[b * 3 + tid] = a3;
  }
}

extern "C" void kernel_launch(void* const* d_in, const int* in_sizes, int n_in,
                              void* d_out, int out_size, void* d_ws, size_t ws_size,
                              hipStream_t stream) {
  const float* x      = (const float*)d_in[0];
  const float* w_proj = (const float*)d_in[1];
  const float* b_proj = (const float*)d_in[2];
  const float* w_ih_l0 = (const float*)d_in[3];
  const float* w_hh_l0 = (const float*)d_in[4];
  const float* b_l0    = (const float*)d_in[5];
  const float* w_ih_r  = (const float*)d_in[6];  // [3,2,256,128]
  const float* w_hh_r  = (const float*)d_in[7];  // [3,2,256,64]
  const float* b_r     = (const float*)d_in[8];  // [3,2,256]
  const float* w_attn  = (const float*)d_in[9];
  const float* g1  = (const float*)d_in[11];
  const float* be1 = (const float*)d_in[12];
  const float* m1  = (const float*)d_in[13];
  const float* v1  = (const float*)d_in[14];
  const float* w1  = (const float*)d_in[15];
  const float* b1  = (const float*)d_in[16];
  const float* w2  = (const float*)d_in[17];
  const float* b2  = (const float*)d_in[18];
  const float* g2  = (const float*)d_in[19];
  const float* be2 = (const float*)d_in[20];
  const float* m2  = (const float*)d_in[21];
  const float* v2  = (const float*)d_in[22];
  const float* w3  = (const float*)d_in[23];
  const float* b3  = (const float*)d_in[24];
  float* out = (float*)d_out;

  const size_t PRE_FLOATS = (size_t)T_LEN * BATCH * 512;  // 537 MB
  const size_t BUF_FLOATS = (size_t)T_LEN * BATCH * 128;  // 134 MB
  const size_t need = (PRE_FLOATS + 2 * BUF_FLOATS) * sizeof(float);

  if (ws_size >= need) {
    // ---- new path: precomputed-pre GEMM + barrier-free single-wave recurrence
    float* PRE  = (float*)d_ws;
    float* bufA = PRE + PRE_FLOATS;
    float* bufB = bufA + BUF_FLOATS;
    float* in0 = bufB;     // [T,B,64]; dead once lstm layer1 writes bufB
    float* pooled = bufA;  // dead region after last layer reads bufA

    dim3 gg(T_LEN * BATCH / 64, 8);
    proj_kernel<<<T_LEN * BATCH / 4, 256, 0, stream>>>(x, w_proj, b_proj, in0);
    pre_gemm<64><<<gg, 256, 0, stream>>>(in0, w_ih_l0, b_l0, PRE);
    lstm_seq<<<256, 64, 0, stream>>>(PRE, w_hh_l0, bufA);
    pre_gemm<128><<<gg, 256, 0, stream>>>(bufA, w_ih_r, b_r, PRE);
    lstm_seq<<<256, 64, 0, stream>>>(PRE, w_hh_r, bufB);
    pre_gemm<128><<<gg, 256, 0, stream>>>(bufB, w_ih_r + 65536, b_r + 512, PRE);
    lstm_seq<<<256, 64, 0, stream>>>(PRE, w_hh_r + 32768, bufA);
    pre_gemm<128><<<gg, 256, 0, stream>>>(bufA, w_ih_r + 131072, b_r + 1024, PRE);
    lstm_seq<<<256, 64, 0, stream>>>(PRE, w_hh_r + 65536, bufB);
    attn_kernel<<<BATCH, 256, 0, stream>>>(bufB, w_attn, pooled);
    head_kernel<<<BATCH, 128, 0, stream>>>(pooled, g1, be1, m1, v1, w1, b1, w2, b2,
                                           g2, be2, m2, v2, w3, b3, out);
  } else {
    // ---- fallback: R6 path (268 MB ws)
    float* bufA = (float*)d_ws;
    float* bufB = bufA + BUF_FLOATS;
    float* in0 = bufB;
    float* pooled = bufA;

    proj_kernel<<<T_LEN * BATCH / 4, 256, 0, stream>>>(x, w_proj, b_proj, in0);
    lstm_kernel<64><<<256, 768, 0, stream>>>(in0, bufA, w_ih_l0, w_hh_l0, b_l0);
    lstm_kernel<128><<<256, 768, 0, stream>>>(bufA, bufB, w_ih_r, w_hh_r, b_r);
    lstm_kernel<128><<<256, 768, 0, stream>>>(bufB, bufA, w_ih_r + 65536, w_hh_r + 32768, b_r + 512);
    lstm_kernel<128><<<256, 768, 0, stream>>>(bufA, bufB, w_ih_r + 131072, w_hh_r + 65536, b_r + 1024);
    attn_kernel<<<BATCH, 256, 0, stream>>>(bufB, w_attn, pooled);
    head_kernel<<<BATCH, 128, 0, stream>>>(pooled, g1, be1, m1, v1, w1, b1, w2, b2,
                                           g2, be2, m2, v2, w3, b3, out);
  }
}